// Round 15
// baseline (496.493 us; speedup 1.0000x reference)
//
#include <hip/hip_runtime.h>
#include <hip/hip_bf16.h>
#include <cstdint>

static constexpr int N_  = 16384;
static constexpr int E_  = 131072;
static constexpr int D_  = 768;
static constexpr int D2_ = 1536;
static constexpr int DSQ_ = D_ * D_;

// ---------------- SAFE-path workspace layout (r14, ~218.8 MB) ----------------
static constexpr size_t S_XB   = 0;            // N*D bf16    = 25165824
static constexpr size_t S_WBT  = 25165824;     // 9*D*D bf16  = 10616832
static constexpr size_t S_WLT  = 39321600;     // D*2D bf16   = 2359296
static constexpr size_t S_NB16 = 41680896;     // N*2D bf16   = 50331648
static constexpr size_t S_Y3   = 92012544;     // 3 * N*D bf16 = 75497472
static constexpr size_t S_ZB   = 92012544;     // N*D bf16 (reuses Y3)
static constexpr size_t S_N1C  = 192675840;    // N*D bf16 carry
static constexpr size_t S_PAY  = 217841664;    // E int32
static constexpr size_t S_CNT  = 218365952;    // N*4 int32
static constexpr size_t S_CURH = 218628096;    // N int32
static constexpr size_t S_CURU = 218693632;    // N int32
static constexpr size_t S_BASE = 218759168;    // (N+1) int32 (padded)
static constexpr size_t S_BC   = 218824736;    // 512 int32
static constexpr size_t S_SCAN = 218826784;    // 513 int32

// ---------------- BIG-path workspace layout (~240.5 MB) ----------------
static constexpr size_t B_XB   = 0;
static constexpr size_t B_WBT  = 25165824;
static constexpr size_t B_WLT  = 35782656;
static constexpr size_t B_NB16 = 38141952;     // + 50331648 = 88473600
static constexpr size_t B_PAY  = 88473600;
static constexpr size_t B_CNT  = 88997888;
static constexpr size_t B_CURH = 89260032;
static constexpr size_t B_CURU = 89325568;
static constexpr size_t B_BASE = 89391104;     // padded to 65568
static constexpr size_t B_BC   = 89456672;
static constexpr size_t B_SCAN = 89458720;
static constexpr size_t B_YBIG = 89460992;     // 6 * N*D bf16 = 150994944
static constexpr size_t B_NEED = 240455936;    // B_YBIG + 150994944

typedef __attribute__((ext_vector_type(8))) short short8v;
typedef __attribute__((ext_vector_type(4))) float floatx4;

__device__ __forceinline__ void gld16(const void* g, void* l) {
  __builtin_amdgcn_global_load_lds(
      (const __attribute__((address_space(1))) unsigned int*)g,
      (__attribute__((address_space(3))) unsigned int*)l, 16, 0, 0);
}

__device__ __forceinline__ float b2f(short u) {
  union { unsigned int i; float f; } x;
  x.i = ((unsigned int)(unsigned short)u) << 16;
  return x.f;
}

__device__ __forceinline__ float wave_sum(float v) {
#pragma unroll
  for (int o = 32; o; o >>= 1) v += __shfl_down(v, o, 64);
  return v;
}

// y in [0,9): WbT[fb][h][d] = W_f[b][d][h].  y in {9,10}: W_linT[h][k] =
// W_lin[k][h] (288 tiles split across two y rows). LDS 64x64 transpose.
__global__ __launch_bounds__(256) void wprep_kernel(
    const float* __restrict__ Wt, const float* __restrict__ Wu,
    const float* __restrict__ Wd, const float* __restrict__ Wl,
    __hip_bfloat16* __restrict__ WbT, __hip_bfloat16* __restrict__ WlT) {
  __shared__ float tile[64][65];
  int y = blockIdx.y;
  int tid = threadIdx.x;
  if (y < 9) {
    int f = y / 3, b = y % 3;
    const float* W = ((f == 0) ? Wt : ((f == 1) ? Wu : Wd)) + (size_t)b * DSQ_;
    int dt = (blockIdx.x / 12) * 64;
    int ht = (blockIdx.x % 12) * 64;
#pragma unroll
    for (int jj = 0; jj < 16; jj++) {
      int idx = jj * 256 + tid;
      int rr = idx >> 6, cc = idx & 63;
      tile[rr][cc] = W[(size_t)(dt + rr) * D_ + ht + cc];
    }
    __syncthreads();
#pragma unroll
    for (int jj = 0; jj < 16; jj++) {
      int idx = jj * 256 + tid;
      int hh = idx >> 6, dd = idx & 63;
      WbT[(size_t)y * DSQ_ + (size_t)(ht + hh) * D_ + dt + dd] =
          __float2bfloat16(tile[dd][hh]);
    }
  } else {
    int idx0 = (y - 9) * 144 + blockIdx.x;   // 0..287
    int kt = (idx0 % 24) * 64;
    int ht = (idx0 / 24) * 64;
#pragma unroll
    for (int jj = 0; jj < 16; jj++) {
      int idx = jj * 256 + tid;
      int rr = idx >> 6, cc = idx & 63;      // rr over k, cc over h
      tile[rr][cc] = Wl[(size_t)(kt + rr) * D_ + ht + cc];
    }
    __syncthreads();
#pragma unroll
    for (int jj = 0; jj < 16; jj++) {
      int idx = jj * 256 + tid;
      int hh = idx >> 6, dd = idx & 63;
      WlT[(size_t)(ht + hh) * D2_ + kt + dd] = __float2bfloat16(tile[dd][hh]);
    }
  }
}

// LayerNorm, float4 loads / short4 stores; 192 of 256 threads carry 4 elems.
__global__ __launch_bounds__(256) void ln_kernel(
    const float* __restrict__ h, const float* __restrict__ gamma,
    const float* __restrict__ beta, __hip_bfloat16* __restrict__ x) {
  int v = blockIdx.x, tid = threadIdx.x;
  float e[4] = {0.f, 0.f, 0.f, 0.f};
  float g[4], bta[4];
  if (tid < 192) {
    float4 a = *(const float4*)(h + (size_t)v * D_ + tid * 4);
    e[0] = a.x; e[1] = a.y; e[2] = a.z; e[3] = a.w;
    float4 gg = *(const float4*)(gamma + tid * 4);
    float4 bb = *(const float4*)(beta + tid * 4);
    g[0] = gg.x; g[1] = gg.y; g[2] = gg.z; g[3] = gg.w;
    bta[0] = bb.x; bta[1] = bb.y; bta[2] = bb.z; bta[3] = bb.w;
  }
  float s = e[0] + e[1] + e[2] + e[3];
  float q = e[0] * e[0] + e[1] * e[1] + e[2] * e[2] + e[3] * e[3];
  __shared__ float red[8];
  __shared__ float mv[2];
  float ws_ = wave_sum(s), wq = wave_sum(q);
  int lane = tid & 63, w = tid >> 6;
  if (lane == 0) { red[w] = ws_; red[4 + w] = wq; }
  __syncthreads();
  if (tid == 0) {
    float S = red[0] + red[1] + red[2] + red[3];
    float Q = red[4] + red[5] + red[6] + red[7];
    float mu = S * (1.0f / D_);
    float var = Q * (1.0f / D_) - mu * mu;
    mv[0] = mu;
    mv[1] = rsqrtf(var + 1e-5f);
  }
  __syncthreads();
  if (tid < 192) {
    float mu = mv[0], rstd = mv[1];
    __hip_bfloat16 o[4];
#pragma unroll
    for (int i = 0; i < 4; i++)
      o[i] = __float2bfloat16((e[i] - mu) * rstd * g[i] + bta[i]);
    *(short4*)(x + (size_t)v * D_ + tid * 4) = *(const short4*)o;
  }
}

// per-block hete counts + (dst,etype) histogram
__global__ __launch_bounds__(256) void edge_a_kernel(
    const int* __restrict__ hete, const int* __restrict__ dst,
    const int* __restrict__ etype, int* __restrict__ blockcnt,
    int* __restrict__ cnt4) {
  int j = blockIdx.x * 256 + threadIdx.x;
  int flag = hete[j] > 0;
  unsigned long long m = __ballot(flag);
  __shared__ int wsum[4];
  int lane = threadIdx.x & 63, w = threadIdx.x >> 6;
  if (lane == 0) wsum[w] = __popcll(m);
  __syncthreads();
  if (threadIdx.x == 0)
    blockcnt[blockIdx.x] = wsum[0] + wsum[1] + wsum[2] + wsum[3];
  atomicAdd(&cnt4[dst[j] * 4 + etype[j]], 1);
}

// block 0: exclusive scan over 512 blockcnt (+ total K at [512]).
// block 1: base[v] = exclusive prefix of deg[v]; base[N] = E.
__global__ __launch_bounds__(1024) void fused_scan_kernel(
    const int* __restrict__ blockcnt, int* __restrict__ scanout,
    const int* __restrict__ cnt4, int* __restrict__ base) {
  int t = threadIdx.x;
  if (blockIdx.x == 0) {
    __shared__ int s[1024];
    int v = (t < 512) ? blockcnt[t] : 0;
    s[t] = v;
    __syncthreads();
    for (int o = 1; o < 512; o <<= 1) {
      int add = (t >= o) ? s[t - o] : 0;
      __syncthreads();
      s[t] += add;
      __syncthreads();
    }
    if (t < 512) scanout[t] = s[t] - v;
    if (t == 511) scanout[512] = s[511];
  } else {
    __shared__ int s[1024];
    int loc[16];
    int sum = 0;
#pragma unroll
    for (int i = 0; i < 16; i++) {
      int v = t * 16 + i;
      int d = cnt4[v * 4] + cnt4[v * 4 + 1] + cnt4[v * 4 + 2] + cnt4[v * 4 + 3];
      loc[i] = sum;
      sum += d;
    }
    s[t] = sum;
    __syncthreads();
    for (int o = 1; o < 1024; o <<= 1) {
      int add = (t >= o) ? s[t - o] : 0;
      __syncthreads();
      s[t] += add;
      __syncthreads();
    }
    int pre = t ? s[t - 1] : 0;
#pragma unroll
    for (int i = 0; i < 16; i++) base[t * 16 + i] = pre + loc[i];
    if (t == 1023) base[N_] = s[1023];
  }
}

// Fused edge_b + edge_sort, two-ended bucket fill (hete ascending from
// base[v], homo descending from base[v+1]-1). payload = etype<<14 | src.
__global__ __launch_bounds__(256) void edge_bsort_kernel(
    const int* __restrict__ hete, const int* __restrict__ dst,
    const int* __restrict__ src, const int* __restrict__ etype,
    const int* __restrict__ scanout, const int* __restrict__ base,
    int* __restrict__ curH, int* __restrict__ curU,
    int* __restrict__ payload) {
  int j = blockIdx.x * 256 + threadIdx.x;
  int flag = hete[j] > 0;
  unsigned long long m = __ballot(flag);
  __shared__ int wsum[4];
  int lane = threadIdx.x & 63, w = threadIdx.x >> 6;
  if (lane == 0) wsum[w] = __popcll(m);
  __syncthreads();
  int wpre = 0;
#pragma unroll
  for (int i = 0; i < 4; i++) wpre += (i < w) ? wsum[i] : 0;
  int lpre = __popcll(m & ((1ull << lane) - 1ull));
  int hcum = scanout[blockIdx.x] + wpre + lpre;
  int K = scanout[512];
  int e = flag ? hcum : (K + j - hcum);
  int v = dst[e];
  int p;
  if (flag) p = base[v] + atomicAdd(&curH[v], 1);
  else      p = base[v + 1] - 1 - atomicAdd(&curU[v], 1);
  payload[p] = (etype[j] << 14) | src[j];
}

// SAFE path gather: one family segment per launch (r14 semantics).
template <bool FIRST, int SEG>
__global__ __launch_bounds__(256) void gather_n1_kernel(
    const __hip_bfloat16* __restrict__ Y, const float* __restrict__ coeff,
    const int* __restrict__ base, const int* __restrict__ hcnt,
    const int* __restrict__ payload, __hip_bfloat16* __restrict__ n1c,
    __hip_bfloat16* __restrict__ nb16) {
  int wv = threadIdx.x >> 6, lane = threadIdx.x & 63;
  int v = blockIdx.x * 4 + wv;
  int bh = base[v] + hcnt[v];
  int lo = (SEG == 0) ? base[v] : bh;
  int hi = (SEG == 0) ? bh : base[v + 1];
  float cf[12];
#pragma unroll
  for (int i = 0; i < 12; i++) cf[i] = coeff[i];
  float acc[12];
  if (FIRST) {
#pragma unroll
    for (int i = 0; i < 12; i++) acc[i] = 0.f;
  } else {
    short8v a8 = *(const short8v*)(n1c + (size_t)v * D_ + lane * 8);
    short4  b4 = *(const short4*)(n1c + (size_t)v * D_ + 512 + lane * 4);
#pragma unroll
    for (int i = 0; i < 8; i++) acc[i] = b2f(a8[i]);
    acc[8] = b2f(b4.x); acc[9] = b2f(b4.y);
    acc[10] = b2f(b4.z); acc[11] = b2f(b4.w);
  }
  const size_t YS = (size_t)N_ * D_;
  for (int idx = lo; idx < hi; ++idx) {
    int pl = payload[idx];
    int t = pl >> 14;
    float c0 = cf[t * 3], c1 = cf[t * 3 + 1], c2 = cf[t * 3 + 2];
    const __hip_bfloat16* r0 = Y + (size_t)(pl & 16383) * D_;
    short8v a0 = *(const short8v*)(r0 + lane * 8);
    short8v a1 = *(const short8v*)(r0 + YS + lane * 8);
    short8v a2 = *(const short8v*)(r0 + 2 * YS + lane * 8);
    short4  b0v = *(const short4*)(r0 + 512 + lane * 4);
    short4  b1v = *(const short4*)(r0 + YS + 512 + lane * 4);
    short4  b2v = *(const short4*)(r0 + 2 * YS + 512 + lane * 4);
#pragma unroll
    for (int i = 0; i < 8; i++)
      acc[i] += fmaxf(c0 * b2f(a0[i]) + c1 * b2f(a1[i]) + c2 * b2f(a2[i]), 0.f);
    acc[8]  += fmaxf(c0 * b2f(b0v.x) + c1 * b2f(b1v.x) + c2 * b2f(b2v.x), 0.f);
    acc[9]  += fmaxf(c0 * b2f(b0v.y) + c1 * b2f(b1v.y) + c2 * b2f(b2v.y), 0.f);
    acc[10] += fmaxf(c0 * b2f(b0v.z) + c1 * b2f(b1v.z) + c2 * b2f(b2v.z), 0.f);
    acc[11] += fmaxf(c0 * b2f(b0v.w) + c1 * b2f(b1v.w) + c2 * b2f(b2v.w), 0.f);
  }
  __hip_bfloat16 o[12];
#pragma unroll
  for (int i = 0; i < 12; i++) o[i] = __float2bfloat16(acc[i]);
  if (FIRST) {
    *(short8v*)(n1c + (size_t)v * D_ + lane * 8) = *(const short8v*)o;
    *(short4*)(n1c + (size_t)v * D_ + 512 + lane * 4) = *(const short4*)(o + 8);
  } else {
    *(short8v*)(nb16 + (size_t)v * D2_ + lane * 8) = *(const short8v*)o;
    *(short4*)(nb16 + (size_t)v * D2_ + 512 + lane * 4) = *(const short4*)(o + 8);
  }
}

// BIG path gather: both families in one pass; Yt = text bases (3 slots),
// Yu = user bases (3 slots); no carry buffer.
__global__ __launch_bounds__(256) void gather_merged_kernel(
    const __hip_bfloat16* __restrict__ Yt, const __hip_bfloat16* __restrict__ Yu,
    const float* __restrict__ c_text, const float* __restrict__ c_user,
    const int* __restrict__ base, const int* __restrict__ hcnt,
    const int* __restrict__ payload, __hip_bfloat16* __restrict__ nb16) {
  int wv = threadIdx.x >> 6, lane = threadIdx.x & 63;
  int v = blockIdx.x * 4 + wv;
  int lo = base[v];
  int bh = lo + hcnt[v];
  int hi = base[v + 1];
  float cf[24];
#pragma unroll
  for (int i = 0; i < 12; i++) { cf[i] = c_text[i]; cf[12 + i] = c_user[i]; }
  float acc[12];
#pragma unroll
  for (int i = 0; i < 12; i++) acc[i] = 0.f;
  const size_t YS = (size_t)N_ * D_;
  for (int idx = lo; idx < hi; ++idx) {
    int pl = payload[idx];
    bool isU = idx >= bh;
    const __hip_bfloat16* Y = isU ? Yu : Yt;
    int t = pl >> 14;
    const float* c = cf + (isU ? 12 : 0) + t * 3;
    float c0 = c[0], c1 = c[1], c2 = c[2];
    const __hip_bfloat16* r0 = Y + (size_t)(pl & 16383) * D_;
    short8v a0 = *(const short8v*)(r0 + lane * 8);
    short8v a1 = *(const short8v*)(r0 + YS + lane * 8);
    short8v a2 = *(const short8v*)(r0 + 2 * YS + lane * 8);
    short4  b0v = *(const short4*)(r0 + 512 + lane * 4);
    short4  b1v = *(const short4*)(r0 + YS + 512 + lane * 4);
    short4  b2v = *(const short4*)(r0 + 2 * YS + 512 + lane * 4);
#pragma unroll
    for (int i = 0; i < 8; i++)
      acc[i] += fmaxf(c0 * b2f(a0[i]) + c1 * b2f(a1[i]) + c2 * b2f(a2[i]), 0.f);
    acc[8]  += fmaxf(c0 * b2f(b0v.x) + c1 * b2f(b1v.x) + c2 * b2f(b2v.x), 0.f);
    acc[9]  += fmaxf(c0 * b2f(b0v.y) + c1 * b2f(b1v.y) + c2 * b2f(b2v.y), 0.f);
    acc[10] += fmaxf(c0 * b2f(b0v.z) + c1 * b2f(b1v.z) + c2 * b2f(b2v.z), 0.f);
    acc[11] += fmaxf(c0 * b2f(b0v.w) + c1 * b2f(b1v.w) + c2 * b2f(b2v.w), 0.f);
  }
  __hip_bfloat16 o[12];
#pragma unroll
  for (int i = 0; i < 12; i++) o[i] = __float2bfloat16(acc[i]);
  *(short8v*)(nb16 + (size_t)v * D2_ + lane * 8) = *(const short8v*)o;
  *(short4*)(nb16 + (size_t)v * D2_ + 512 + lane * 4) = *(const short4*)(o + 8);
}

// nb16[v][768+k] = sum_t cnt4[v,t] * relu(sum_b cd[t,b] * Y[b][v][k])
__global__ __launch_bounds__(256) void combine_n2_kernel(
    const __hip_bfloat16* __restrict__ Y, const float* __restrict__ cd,
    const int* __restrict__ cnt4, __hip_bfloat16* __restrict__ nb16) {
  size_t i = ((size_t)blockIdx.x * 256 + threadIdx.x) * 8;
  int v = (int)(i / D_);
  int k = (int)(i % D_);
  const size_t YS = (size_t)N_ * D_;
  short8v y0 = *(const short8v*)(Y + i);
  short8v y1 = *(const short8v*)(Y + YS + i);
  short8v y2 = *(const short8v*)(Y + 2 * YS + i);
  float f0[8], f1[8], f2[8];
#pragma unroll
  for (int j = 0; j < 8; j++) {
    f0[j] = b2f(y0[j]); f1[j] = b2f(y1[j]); f2[j] = b2f(y2[j]);
  }
  float acc[8] = {0.f, 0.f, 0.f, 0.f, 0.f, 0.f, 0.f, 0.f};
#pragma unroll
  for (int t = 0; t < 4; t++) {
    float c = (float)cnt4[v * 4 + t];
    if (c != 0.f) {
      float d0 = cd[t * 3], d1 = cd[t * 3 + 1], d2 = cd[t * 3 + 2];
#pragma unroll
      for (int j = 0; j < 8; j++)
        acc[j] += c * fmaxf(d0 * f0[j] + d1 * f1[j] + d2 * f2[j], 0.f);
    }
  }
  __hip_bfloat16 o[8];
#pragma unroll
  for (int j = 0; j < 8; j++) o[j] = __float2bfloat16(acc[j]);
  *(short8v*)(nb16 + (size_t)v * D2_ + D_ + k) = *(const short8v*)o;
}

// C[z][M,N] = op(A @ BT[z]^T (+bias)), op = relu iff RELU. bf16 out, z folded
// into the XCD swizzle. 128x128 tile, BK=64, 4 waves, 16x16x32 MFMA,
// XOR-swizzled LDS, LDS-staged coalesced epilogue.
template <bool BIAS, bool RELU>
__global__ __launch_bounds__(256) void gemm_mfma_kernel(
    const __hip_bfloat16* __restrict__ A, const __hip_bfloat16* __restrict__ BT0,
    const float* __restrict__ bias, __hip_bfloat16* __restrict__ C0,
    int M, int N, int K, size_t strideB, size_t strideC) {
  __shared__ char lds[32768];
  char* As = lds;
  char* Bs = lds + 16384;
  int tid = threadIdx.x;
  int lane = tid & 63;
  int wv = tid >> 6;
  int wr = wv >> 1, wc = wv & 1;
  int gx = gridDim.x, gz = gridDim.z;
  int nwg = gx * gridDim.y * gz;
  int id = (blockIdx.z * gridDim.y + blockIdx.y) * gx + blockIdx.x;
  int s = (id & 7) * (nwg >> 3) + (id >> 3);
  int bx = s % gx;
  int rem = s / gx;
  int z = rem % gz;
  int by = rem / gz;
  const __hip_bfloat16* BT = BT0 + (size_t)z * strideB;
  int row0 = by * 128, col0 = bx * 128;
  int r_ = tid >> 3;
  int s_ = tid & 7;

  floatx4 acc[4][4];
#pragma unroll
  for (int i = 0; i < 4; i++)
#pragma unroll
    for (int j = 0; j < 4; j++) acc[i][j] = floatx4{0.f, 0.f, 0.f, 0.f};

  for (int k0 = 0; k0 < K; k0 += 64) {
    __syncthreads();
#pragma unroll
    for (int is = 0; is < 4; is++) {
      int r = is * 32 + r_;
      int sp = s_ ^ (r & 7);
      gld16(A  + (size_t)(row0 + r) * K + k0 + sp * 8, As + is * 4096 + tid * 16);
      gld16(BT + (size_t)(col0 + r) * K + k0 + sp * 8, Bs + is * 4096 + tid * 16);
    }
    __syncthreads();
#pragma unroll
    for (int kk = 0; kk < 64; kk += 32) {
      int p = (kk >> 3) + (lane >> 4);
      short8v af[4], bf[4];
#pragma unroll
      for (int m = 0; m < 4; m++) {
        int ra = wr * 64 + m * 16 + (lane & 15);
        af[m] = *(const short8v*)(As + ra * 128 + ((p ^ (ra & 7)) << 4));
        int rb = wc * 64 + m * 16 + (lane & 15);
        bf[m] = *(const short8v*)(Bs + rb * 128 + ((p ^ (rb & 7)) << 4));
      }
#pragma unroll
      for (int m = 0; m < 4; m++)
#pragma unroll
        for (int n = 0; n < 4; n++)
          acc[m][n] = __builtin_amdgcn_mfma_f32_16x16x32_bf16(
              af[m], bf[n], acc[m][n], 0, 0, 0);
    }
  }
  __syncthreads();
  char* cs = lds + wv * 8192;
#pragma unroll
  for (int m = 0; m < 4; m++) {
#pragma unroll
    for (int n = 0; n < 4; n++) {
      int c = n * 16 + (lane & 15);
      float bv = BIAS ? bias[col0 + wc * 64 + c] : 0.f;
#pragma unroll
      for (int q = 0; q < 4; q++) {
        int r = m * 16 + (lane >> 4) * 4 + q;
        float v = acc[m][n][q] + bv;
        if (RELU) v = fmaxf(v, 0.f);
        int byte = r * 128 + ((((c >> 3) + r) & 7) << 4) + ((c & 7) << 1);
        *(__hip_bfloat16*)(cs + byte) = __float2bfloat16(v);
      }
    }
  }
  __hip_bfloat16* C = C0 + (size_t)z * strideC;
#pragma unroll
  for (int i = 0; i < 8; i++) {
    int r = i * 8 + (lane >> 3);
    int s8 = lane & 7;
    int p = (s8 + r) & 7;
    short8v v = *(const short8v*)(cs + r * 128 + (p << 4));
    int grow = row0 + wr * 64 + r;
    int gcol = col0 + wc * 64 + s8 * 8;
    *(short8v*)(C + (size_t)grow * N + gcol) = v;
  }
}

// row L2-normalize: z bf16 -> out fp32.
__global__ __launch_bounds__(256) void norm_kernel(
    const __hip_bfloat16* __restrict__ z, float* __restrict__ out) {
  int v = blockIdx.x, tid = threadIdx.x;
  float e[4] = {0.f, 0.f, 0.f, 0.f};
  if (tid < 192) {
    short4 a = *(const short4*)(z + (size_t)v * D_ + tid * 4);
    e[0] = b2f(a.x); e[1] = b2f(a.y); e[2] = b2f(a.z); e[3] = b2f(a.w);
  }
  float q = e[0] * e[0] + e[1] * e[1] + e[2] * e[2] + e[3] * e[3];
  __shared__ float red[4];
  __shared__ float sc;
  float wq = wave_sum(q);
  int lane = tid & 63, w = tid >> 6;
  if (lane == 0) red[w] = wq;
  __syncthreads();
  if (tid == 0) {
    float S = red[0] + red[1] + red[2] + red[3];
    float norm = sqrtf(S);
    sc = (norm == 0.f) ? 1.f : (1.f / norm);
  }
  __syncthreads();
  if (tid < 192) {
    float s = sc;
    float4 o = {e[0] * s, e[1] * s, e[2] * s, e[3] * s};
    *(float4*)(out + (size_t)v * D_ + tid * 4) = o;
  }
}

extern "C" void kernel_launch(void* const* d_in, const int* in_sizes, int n_in,
                              void* d_out, int out_size, void* d_ws,
                              size_t ws_size, hipStream_t stream) {
  (void)in_sizes; (void)n_in; (void)out_size;
  const float* h      = (const float*)d_in[0];
  const float* W_text = (const float*)d_in[1];
  const float* c_text = (const float*)d_in[2];
  const float* W_user = (const float*)d_in[3];
  const float* c_user = (const float*)d_in[4];
  const float* W_dst  = (const float*)d_in[5];
  const float* c_dst  = (const float*)d_in[6];
  const float* gamma  = (const float*)d_in[7];
  const float* beta   = (const float*)d_in[8];
  const float* W_lin  = (const float*)d_in[9];
  const float* b_lin  = (const float*)d_in[10];
  const int* src      = (const int*)d_in[11];
  const int* dst      = (const int*)d_in[12];
  const int* etype    = (const int*)d_in[13];
  const int* hete     = (const int*)d_in[14];
  float* out          = (float*)d_out;

  const bool big = ws_size >= (size_t)B_NEED;
  char* ws = (char*)d_ws;
  const size_t HSTRIDE = (size_t)N_ * D_;

  __hip_bfloat16* xb   = (__hip_bfloat16*)(ws + (big ? B_XB : S_XB));
  __hip_bfloat16* WbT  = (__hip_bfloat16*)(ws + (big ? B_WBT : S_WBT));
  __hip_bfloat16* WlT  = (__hip_bfloat16*)(ws + (big ? B_WLT : S_WLT));
  __hip_bfloat16* nb16 = (__hip_bfloat16*)(ws + (big ? B_NB16 : S_NB16));
  int* payload  = (int*)(ws + (big ? B_PAY : S_PAY));
  int* cnt4     = (int*)(ws + (big ? B_CNT : S_CNT));
  int* curH     = (int*)(ws + (big ? B_CURH : S_CURH));
  int* curU     = (int*)(ws + (big ? B_CURU : S_CURU));
  int* base     = (int*)(ws + (big ? B_BASE : S_BASE));
  int* blockcnt = (int*)(ws + (big ? B_BC : S_BC));
  int* scanout  = (int*)(ws + (big ? B_SCAN : S_SCAN));

  // shared preprocessing
  hipMemsetAsync(cnt4, 0, 262144 + 65536 + 65536, stream);
  wprep_kernel<<<dim3(144, 11), 256, 0, stream>>>(W_text, W_user, W_dst,
                                                  W_lin, WbT, WlT);
  ln_kernel<<<N_, 256, 0, stream>>>(h, gamma, beta, xb);
  edge_a_kernel<<<E_ / 256, 256, 0, stream>>>(hete, dst, etype, blockcnt, cnt4);
  fused_scan_kernel<<<2, 1024, 0, stream>>>(blockcnt, scanout, cnt4, base);
  edge_bsort_kernel<<<E_ / 256, 256, 0, stream>>>(hete, dst, src, etype,
                                                  scanout, base, curH, curU,
                                                  payload);

  if (big) {
    __hip_bfloat16* Ybig = (__hip_bfloat16*)(ws + B_YBIG);  // 6 slots
    __hip_bfloat16* zbuf = Ybig;
    // dst family -> Ybig[0..3), combine into nb16 right half
    gemm_mfma_kernel<false, false>
        <<<dim3(D_ / 128, N_ / 128, 3), 256, 0, stream>>>(
            xb, WbT + (size_t)6 * DSQ_, nullptr, Ybig, N_, D_, D_, DSQ_,
            HSTRIDE);
    combine_n2_kernel<<<(N_ * D_) / (256 * 8), 256, 0, stream>>>(Ybig, c_dst,
                                                                 cnt4, nb16);
    // both src families in one z=6 launch (text -> slots 0-2, user -> 3-5)
    gemm_mfma_kernel<false, false>
        <<<dim3(D_ / 128, N_ / 128, 6), 256, 0, stream>>>(
            xb, WbT, nullptr, Ybig, N_, D_, D_, DSQ_, HSTRIDE);
    gather_merged_kernel<<<N_ / 4, 256, 0, stream>>>(
        Ybig, Ybig + 3 * HSTRIDE, c_text, c_user, base, curH, payload, nb16);
    // final
    gemm_mfma_kernel<true, true>
        <<<dim3(D_ / 128, N_ / 128, 1), 256, 0, stream>>>(
            nb16, WlT, b_lin, zbuf, N_, D_, D2_, 0, 0);
    norm_kernel<<<N_, 256, 0, stream>>>(zbuf, out);
  } else {
    __hip_bfloat16* Y3   = (__hip_bfloat16*)(ws + S_Y3);
    __hip_bfloat16* zbuf = (__hip_bfloat16*)(ws + S_ZB);
    __hip_bfloat16* n1c  = (__hip_bfloat16*)(ws + S_N1C);
    gemm_mfma_kernel<false, false>
        <<<dim3(D_ / 128, N_ / 128, 3), 256, 0, stream>>>(
            xb, WbT + (size_t)6 * DSQ_, nullptr, Y3, N_, D_, D_, DSQ_,
            HSTRIDE);
    combine_n2_kernel<<<(N_ * D_) / (256 * 8), 256, 0, stream>>>(Y3, c_dst,
                                                                 cnt4, nb16);
    gemm_mfma_kernel<false, false>
        <<<dim3(D_ / 128, N_ / 128, 3), 256, 0, stream>>>(
            xb, WbT, nullptr, Y3, N_, D_, D_, DSQ_, HSTRIDE);
    gather_n1_kernel<true, 0><<<N_ / 4, 256, 0, stream>>>(
        Y3, c_text, base, curH, payload, n1c, nb16);
    gemm_mfma_kernel<false, false>
        <<<dim3(D_ / 128, N_ / 128, 3), 256, 0, stream>>>(
            xb, WbT + (size_t)3 * DSQ_, nullptr, Y3, N_, D_, D_, DSQ_,
            HSTRIDE);
    gather_n1_kernel<false, 1><<<N_ / 4, 256, 0, stream>>>(
        Y3, c_user, base, curH, payload, n1c, nb16);
    gemm_mfma_kernel<true, true>
        <<<dim3(D_ / 128, N_ / 128, 1), 256, 0, stream>>>(
            nb16, WlT, b_lin, zbuf, N_, D_, D2_, 0, 0);
    norm_kernel<<<N_, 256, 0, stream>>>(zbuf, out);
  }
}

// Round 16
// 456.527 us; speedup vs baseline: 1.0875x; 1.0875x over previous
//
#include <hip/hip_runtime.h>
#include <hip/hip_bf16.h>
#include <cstdint>

static constexpr int N_  = 16384;
static constexpr int E_  = 131072;
static constexpr int D_  = 768;
static constexpr int D2_ = 1536;
static constexpr int D3_ = 2304;   // interleaved Y row stride
static constexpr int DSQ_ = D_ * D_;

// ---------------- workspace layout (bytes), ~218.8 MB ----------------
static constexpr size_t OFF_XB   = 0;            // N*D bf16    = 25165824
static constexpr size_t OFF_WBT  = 25165824;     // 9*D*D bf16  = 10616832
static constexpr size_t OFF_WLT  = 39321600;     // D*2D bf16   = 2359296
static constexpr size_t OFF_NB16 = 41680896;     // N*2D bf16   = 50331648
static constexpr size_t OFF_Y3   = 92012544;     // N*3*D bf16  = 75497472 (interleaved)
static constexpr size_t OFF_ZB   = 92012544;     // N*D bf16 (reuses Y3)
static constexpr size_t OFF_N1C  = 192675840;    // N*D bf16 carry
static constexpr size_t OFF_PAY  = 217841664;    // E int32
static constexpr size_t OFF_CNT  = 218365952;    // N*4 int32   } one
static constexpr size_t OFF_CURH = 218628096;    // N int32     } memset
static constexpr size_t OFF_CURU = 218693632;    // N int32     } span
static constexpr size_t OFF_BASE = 218759168;    // (N+1) int32 (padded)
static constexpr size_t OFF_BC   = 218824736;    // 512 int32
static constexpr size_t OFF_SCAN = 218826784;    // 513 int32

typedef __attribute__((ext_vector_type(8))) short short8v;
typedef __attribute__((ext_vector_type(4))) float floatx4;

__device__ __forceinline__ void gld16(const void* g, void* l) {
  __builtin_amdgcn_global_load_lds(
      (const __attribute__((address_space(1))) unsigned int*)g,
      (__attribute__((address_space(3))) unsigned int*)l, 16, 0, 0);
}

__device__ __forceinline__ float b2f(short u) {
  union { unsigned int i; float f; } x;
  x.i = ((unsigned int)(unsigned short)u) << 16;
  return x.f;
}

__device__ __forceinline__ float wave_sum(float v) {
#pragma unroll
  for (int o = 32; o; o >>= 1) v += __shfl_down(v, o, 64);
  return v;
}

// y in [0,9): WbT[fb][h][d] = W_f[b][d][h].  y in {9,10}: W_linT[h][k] =
// W_lin[k][h] (288 tiles split across two y rows). LDS 64x64 transpose.
__global__ __launch_bounds__(256) void wprep_kernel(
    const float* __restrict__ Wt, const float* __restrict__ Wu,
    const float* __restrict__ Wd, const float* __restrict__ Wl,
    __hip_bfloat16* __restrict__ WbT, __hip_bfloat16* __restrict__ WlT) {
  __shared__ float tile[64][65];
  int y = blockIdx.y;
  int tid = threadIdx.x;
  if (y < 9) {
    int f = y / 3, b = y % 3;
    const float* W = ((f == 0) ? Wt : ((f == 1) ? Wu : Wd)) + (size_t)b * DSQ_;
    int dt = (blockIdx.x / 12) * 64;
    int ht = (blockIdx.x % 12) * 64;
#pragma unroll
    for (int jj = 0; jj < 16; jj++) {
      int idx = jj * 256 + tid;
      int rr = idx >> 6, cc = idx & 63;
      tile[rr][cc] = W[(size_t)(dt + rr) * D_ + ht + cc];
    }
    __syncthreads();
#pragma unroll
    for (int jj = 0; jj < 16; jj++) {
      int idx = jj * 256 + tid;
      int hh = idx >> 6, dd = idx & 63;
      WbT[(size_t)y * DSQ_ + (size_t)(ht + hh) * D_ + dt + dd] =
          __float2bfloat16(tile[dd][hh]);
    }
  } else {
    int idx0 = (y - 9) * 144 + blockIdx.x;   // 0..287
    int kt = (idx0 % 24) * 64;
    int ht = (idx0 / 24) * 64;
#pragma unroll
    for (int jj = 0; jj < 16; jj++) {
      int idx = jj * 256 + tid;
      int rr = idx >> 6, cc = idx & 63;      // rr over k, cc over h
      tile[rr][cc] = Wl[(size_t)(kt + rr) * D_ + ht + cc];
    }
    __syncthreads();
#pragma unroll
    for (int jj = 0; jj < 16; jj++) {
      int idx = jj * 256 + tid;
      int hh = idx >> 6, dd = idx & 63;
      WlT[(size_t)(ht + hh) * D2_ + kt + dd] = __float2bfloat16(tile[dd][hh]);
    }
  }
}

// LayerNorm, float4 loads / short4 stores; 192 of 256 threads carry 4 elems.
__global__ __launch_bounds__(256) void ln_kernel(
    const float* __restrict__ h, const float* __restrict__ gamma,
    const float* __restrict__ beta, __hip_bfloat16* __restrict__ x) {
  int v = blockIdx.x, tid = threadIdx.x;
  float e[4] = {0.f, 0.f, 0.f, 0.f};
  float g[4], bta[4];
  if (tid < 192) {
    float4 a = *(const float4*)(h + (size_t)v * D_ + tid * 4);
    e[0] = a.x; e[1] = a.y; e[2] = a.z; e[3] = a.w;
    float4 gg = *(const float4*)(gamma + tid * 4);
    float4 bb = *(const float4*)(beta + tid * 4);
    g[0] = gg.x; g[1] = gg.y; g[2] = gg.z; g[3] = gg.w;
    bta[0] = bb.x; bta[1] = bb.y; bta[2] = bb.z; bta[3] = bb.w;
  }
  float s = e[0] + e[1] + e[2] + e[3];
  float q = e[0] * e[0] + e[1] * e[1] + e[2] * e[2] + e[3] * e[3];
  __shared__ float red[8];
  __shared__ float mv[2];
  float ws_ = wave_sum(s), wq = wave_sum(q);
  int lane = tid & 63, w = tid >> 6;
  if (lane == 0) { red[w] = ws_; red[4 + w] = wq; }
  __syncthreads();
  if (tid == 0) {
    float S = red[0] + red[1] + red[2] + red[3];
    float Q = red[4] + red[5] + red[6] + red[7];
    float mu = S * (1.0f / D_);
    float var = Q * (1.0f / D_) - mu * mu;
    mv[0] = mu;
    mv[1] = rsqrtf(var + 1e-5f);
  }
  __syncthreads();
  if (tid < 192) {
    float mu = mv[0], rstd = mv[1];
    __hip_bfloat16 o[4];
#pragma unroll
    for (int i = 0; i < 4; i++)
      o[i] = __float2bfloat16((e[i] - mu) * rstd * g[i] + bta[i]);
    *(short4*)(x + (size_t)v * D_ + tid * 4) = *(const short4*)o;
  }
}

// per-block hete counts + (dst,etype) histogram
__global__ __launch_bounds__(256) void edge_a_kernel(
    const int* __restrict__ hete, const int* __restrict__ dst,
    const int* __restrict__ etype, int* __restrict__ blockcnt,
    int* __restrict__ cnt4) {
  int j = blockIdx.x * 256 + threadIdx.x;
  int flag = hete[j] > 0;
  unsigned long long m = __ballot(flag);
  __shared__ int wsum[4];
  int lane = threadIdx.x & 63, w = threadIdx.x >> 6;
  if (lane == 0) wsum[w] = __popcll(m);
  __syncthreads();
  if (threadIdx.x == 0)
    blockcnt[blockIdx.x] = wsum[0] + wsum[1] + wsum[2] + wsum[3];
  atomicAdd(&cnt4[dst[j] * 4 + etype[j]], 1);
}

// block 0: exclusive scan over 512 blockcnt (+ total K at [512]).
// block 1: base[v] = exclusive prefix of deg[v]; base[N] = E.
__global__ __launch_bounds__(1024) void fused_scan_kernel(
    const int* __restrict__ blockcnt, int* __restrict__ scanout,
    const int* __restrict__ cnt4, int* __restrict__ base) {
  int t = threadIdx.x;
  if (blockIdx.x == 0) {
    __shared__ int s[1024];
    int v = (t < 512) ? blockcnt[t] : 0;
    s[t] = v;
    __syncthreads();
    for (int o = 1; o < 512; o <<= 1) {
      int add = (t >= o) ? s[t - o] : 0;
      __syncthreads();
      s[t] += add;
      __syncthreads();
    }
    if (t < 512) scanout[t] = s[t] - v;
    if (t == 511) scanout[512] = s[511];
  } else {
    __shared__ int s[1024];
    int loc[16];
    int sum = 0;
#pragma unroll
    for (int i = 0; i < 16; i++) {
      int v = t * 16 + i;
      int d = cnt4[v * 4] + cnt4[v * 4 + 1] + cnt4[v * 4 + 2] + cnt4[v * 4 + 3];
      loc[i] = sum;
      sum += d;
    }
    s[t] = sum;
    __syncthreads();
    for (int o = 1; o < 1024; o <<= 1) {
      int add = (t >= o) ? s[t - o] : 0;
      __syncthreads();
      s[t] += add;
      __syncthreads();
    }
    int pre = t ? s[t - 1] : 0;
#pragma unroll
    for (int i = 0; i < 16; i++) base[t * 16 + i] = pre + loc[i];
    if (t == 1023) base[N_] = s[1023];
  }
}

// Fused edge_b + edge_sort, two-ended bucket fill (hete ascending from
// base[v], homo descending from base[v+1]-1). payload = etype<<14 | src.
__global__ __launch_bounds__(256) void edge_bsort_kernel(
    const int* __restrict__ hete, const int* __restrict__ dst,
    const int* __restrict__ src, const int* __restrict__ etype,
    const int* __restrict__ scanout, const int* __restrict__ base,
    int* __restrict__ curH, int* __restrict__ curU,
    int* __restrict__ payload) {
  int j = blockIdx.x * 256 + threadIdx.x;
  int flag = hete[j] > 0;
  unsigned long long m = __ballot(flag);
  __shared__ int wsum[4];
  int lane = threadIdx.x & 63, w = threadIdx.x >> 6;
  if (lane == 0) wsum[w] = __popcll(m);
  __syncthreads();
  int wpre = 0;
#pragma unroll
  for (int i = 0; i < 4; i++) wpre += (i < w) ? wsum[i] : 0;
  int lpre = __popcll(m & ((1ull << lane) - 1ull));
  int hcum = scanout[blockIdx.x] + wpre + lpre;
  int K = scanout[512];
  int e = flag ? hcum : (K + j - hcum);
  int v = dst[e];
  int p;
  if (flag) p = base[v] + atomicAdd(&curH[v], 1);
  else      p = base[v + 1] - 1 - atomicAdd(&curU[v], 1);
  payload[p] = (etype[j] << 14) | src[j];
}

// Gather over one family segment. Y interleaved [v][3][768]: per edge ONE
// contiguous 4.6KB block (3 basis rows). Lane owns elems [lane*8,+8) and
// [512+lane*4,+4) of each row.
template <bool FIRST, int SEG>
__global__ __launch_bounds__(256) void gather_n1_kernel(
    const __hip_bfloat16* __restrict__ Y, const float* __restrict__ coeff,
    const int* __restrict__ base, const int* __restrict__ hcnt,
    const int* __restrict__ payload, __hip_bfloat16* __restrict__ n1c,
    __hip_bfloat16* __restrict__ nb16) {
  int wv = threadIdx.x >> 6, lane = threadIdx.x & 63;
  int v = blockIdx.x * 4 + wv;
  int bh = base[v] + hcnt[v];
  int lo = (SEG == 0) ? base[v] : bh;
  int hi = (SEG == 0) ? bh : base[v + 1];
  float cf[12];
#pragma unroll
  for (int i = 0; i < 12; i++) cf[i] = coeff[i];
  float acc[12];
  if (FIRST) {
#pragma unroll
    for (int i = 0; i < 12; i++) acc[i] = 0.f;
  } else {
    short8v a8 = *(const short8v*)(n1c + (size_t)v * D_ + lane * 8);
    short4  b4 = *(const short4*)(n1c + (size_t)v * D_ + 512 + lane * 4);
#pragma unroll
    for (int i = 0; i < 8; i++) acc[i] = b2f(a8[i]);
    acc[8] = b2f(b4.x); acc[9] = b2f(b4.y);
    acc[10] = b2f(b4.z); acc[11] = b2f(b4.w);
  }
  for (int idx = lo; idx < hi; ++idx) {
    int pl = payload[idx];
    int t = pl >> 14;
    float c0 = cf[t * 3], c1 = cf[t * 3 + 1], c2 = cf[t * 3 + 2];
    const __hip_bfloat16* r0 = Y + (size_t)(pl & 16383) * D3_;
    short8v a0 = *(const short8v*)(r0 + lane * 8);
    short8v a1 = *(const short8v*)(r0 + D_ + lane * 8);
    short8v a2 = *(const short8v*)(r0 + 2 * D_ + lane * 8);
    short4  b0v = *(const short4*)(r0 + 512 + lane * 4);
    short4  b1v = *(const short4*)(r0 + D_ + 512 + lane * 4);
    short4  b2v = *(const short4*)(r0 + 2 * D_ + 512 + lane * 4);
#pragma unroll
    for (int i = 0; i < 8; i++)
      acc[i] += fmaxf(c0 * b2f(a0[i]) + c1 * b2f(a1[i]) + c2 * b2f(a2[i]), 0.f);
    acc[8]  += fmaxf(c0 * b2f(b0v.x) + c1 * b2f(b1v.x) + c2 * b2f(b2v.x), 0.f);
    acc[9]  += fmaxf(c0 * b2f(b0v.y) + c1 * b2f(b1v.y) + c2 * b2f(b2v.y), 0.f);
    acc[10] += fmaxf(c0 * b2f(b0v.z) + c1 * b2f(b1v.z) + c2 * b2f(b2v.z), 0.f);
    acc[11] += fmaxf(c0 * b2f(b0v.w) + c1 * b2f(b1v.w) + c2 * b2f(b2v.w), 0.f);
  }
  __hip_bfloat16 o[12];
#pragma unroll
  for (int i = 0; i < 12; i++) o[i] = __float2bfloat16(acc[i]);
  if (FIRST) {
    *(short8v*)(n1c + (size_t)v * D_ + lane * 8) = *(const short8v*)o;
    *(short4*)(n1c + (size_t)v * D_ + 512 + lane * 4) = *(const short4*)(o + 8);
  } else {
    *(short8v*)(nb16 + (size_t)v * D2_ + lane * 8) = *(const short8v*)o;
    *(short4*)(nb16 + (size_t)v * D2_ + 512 + lane * 4) = *(const short4*)(o + 8);
  }
}

// nb16[v][768+k] = sum_t cnt4[v,t] * relu(sum_b cd[t,b] * Y[v][b][k])
__global__ __launch_bounds__(256) void combine_n2_kernel(
    const __hip_bfloat16* __restrict__ Y, const float* __restrict__ cd,
    const int* __restrict__ cnt4, __hip_bfloat16* __restrict__ nb16) {
  size_t i = ((size_t)blockIdx.x * 256 + threadIdx.x) * 8;
  int v = (int)(i / D_);
  int k = (int)(i % D_);
  const __hip_bfloat16* yr = Y + (size_t)v * D3_ + k;
  short8v y0 = *(const short8v*)(yr);
  short8v y1 = *(const short8v*)(yr + D_);
  short8v y2 = *(const short8v*)(yr + 2 * D_);
  float f0[8], f1[8], f2[8];
#pragma unroll
  for (int j = 0; j < 8; j++) {
    f0[j] = b2f(y0[j]); f1[j] = b2f(y1[j]); f2[j] = b2f(y2[j]);
  }
  float acc[8] = {0.f, 0.f, 0.f, 0.f, 0.f, 0.f, 0.f, 0.f};
#pragma unroll
  for (int t = 0; t < 4; t++) {
    float c = (float)cnt4[v * 4 + t];
    if (c != 0.f) {
      float d0 = cd[t * 3], d1 = cd[t * 3 + 1], d2 = cd[t * 3 + 2];
#pragma unroll
      for (int j = 0; j < 8; j++)
        acc[j] += c * fmaxf(d0 * f0[j] + d1 * f1[j] + d2 * f2[j], 0.f);
    }
  }
  __hip_bfloat16 o[8];
#pragma unroll
  for (int j = 0; j < 8; j++) o[j] = __float2bfloat16(acc[j]);
  *(short8v*)(nb16 + (size_t)v * D2_ + D_ + k) = *(const short8v*)o;
}

// C = op(A @ BT[z]^T (+bias)), op = relu iff RELU. bf16 out. z folded into
// XCD swizzle. C row stride ldC, z column offset zcol (interleaved Y when
// ldC=2304, zcol=768; plain when ldC=N, zcol=0). 128x128 tile, BK=64,
// 4 waves, 16x16x32 MFMA, XOR-swizzled LDS, LDS-staged coalesced epilogue.
template <bool BIAS, bool RELU>
__global__ __launch_bounds__(256) void gemm_mfma_kernel(
    const __hip_bfloat16* __restrict__ A, const __hip_bfloat16* __restrict__ BT0,
    const float* __restrict__ bias, __hip_bfloat16* __restrict__ C0,
    int M, int N, int K, size_t strideB, int ldC, int zcol) {
  __shared__ char lds[32768];
  char* As = lds;
  char* Bs = lds + 16384;
  int tid = threadIdx.x;
  int lane = tid & 63;
  int wv = tid >> 6;
  int wr = wv >> 1, wc = wv & 1;
  int gx = gridDim.x, gz = gridDim.z;
  int nwg = gx * gridDim.y * gz;
  int id = (blockIdx.z * gridDim.y + blockIdx.y) * gx + blockIdx.x;
  int s = (id & 7) * (nwg >> 3) + (id >> 3);
  int bx = s % gx;
  int rem = s / gx;
  int z = rem % gz;
  int by = rem / gz;
  const __hip_bfloat16* BT = BT0 + (size_t)z * strideB;
  int row0 = by * 128, col0 = bx * 128;
  int r_ = tid >> 3;
  int s_ = tid & 7;

  floatx4 acc[4][4];
#pragma unroll
  for (int i = 0; i < 4; i++)
#pragma unroll
    for (int j = 0; j < 4; j++) acc[i][j] = floatx4{0.f, 0.f, 0.f, 0.f};

  for (int k0 = 0; k0 < K; k0 += 64) {
    __syncthreads();
#pragma unroll
    for (int is = 0; is < 4; is++) {
      int r = is * 32 + r_;
      int sp = s_ ^ (r & 7);
      gld16(A  + (size_t)(row0 + r) * K + k0 + sp * 8, As + is * 4096 + tid * 16);
      gld16(BT + (size_t)(col0 + r) * K + k0 + sp * 8, Bs + is * 4096 + tid * 16);
    }
    __syncthreads();
#pragma unroll
    for (int kk = 0; kk < 64; kk += 32) {
      int p = (kk >> 3) + (lane >> 4);
      short8v af[4], bf[4];
#pragma unroll
      for (int m = 0; m < 4; m++) {
        int ra = wr * 64 + m * 16 + (lane & 15);
        af[m] = *(const short8v*)(As + ra * 128 + ((p ^ (ra & 7)) << 4));
        int rb = wc * 64 + m * 16 + (lane & 15);
        bf[m] = *(const short8v*)(Bs + rb * 128 + ((p ^ (rb & 7)) << 4));
      }
#pragma unroll
      for (int m = 0; m < 4; m++)
#pragma unroll
        for (int n = 0; n < 4; n++)
          acc[m][n] = __builtin_amdgcn_mfma_f32_16x16x32_bf16(
              af[m], bf[n], acc[m][n], 0, 0, 0);
    }
  }
  __syncthreads();
  char* cs = lds + wv * 8192;
#pragma unroll
  for (int m = 0; m < 4; m++) {
#pragma unroll
    for (int n = 0; n < 4; n++) {
      int c = n * 16 + (lane & 15);
      float bv = BIAS ? bias[col0 + wc * 64 + c] : 0.f;
#pragma unroll
      for (int q = 0; q < 4; q++) {
        int r = m * 16 + (lane >> 4) * 4 + q;
        float v = acc[m][n][q] + bv;
        if (RELU) v = fmaxf(v, 0.f);
        int byte = r * 128 + ((((c >> 3) + r) & 7) << 4) + ((c & 7) << 1);
        *(__hip_bfloat16*)(cs + byte) = __float2bfloat16(v);
      }
    }
  }
  __hip_bfloat16* C = C0 + (size_t)z * zcol;
#pragma unroll
  for (int i = 0; i < 8; i++) {
    int r = i * 8 + (lane >> 3);
    int s8 = lane & 7;
    int p = (s8 + r) & 7;
    short8v v = *(const short8v*)(cs + r * 128 + (p << 4));
    int grow = row0 + wr * 64 + r;
    int gcol = col0 + wc * 64 + s8 * 8;
    *(short8v*)(C + (size_t)grow * ldC + gcol) = v;
  }
}

// row L2-normalize: z bf16 -> out fp32.
__global__ __launch_bounds__(256) void norm_kernel(
    const __hip_bfloat16* __restrict__ z, float* __restrict__ out) {
  int v = blockIdx.x, tid = threadIdx.x;
  float e[4] = {0.f, 0.f, 0.f, 0.f};
  if (tid < 192) {
    short4 a = *(const short4*)(z + (size_t)v * D_ + tid * 4);
    e[0] = b2f(a.x); e[1] = b2f(a.y); e[2] = b2f(a.z); e[3] = b2f(a.w);
  }
  float q = e[0] * e[0] + e[1] * e[1] + e[2] * e[2] + e[3] * e[3];
  __shared__ float red[4];
  __shared__ float sc;
  float wq = wave_sum(q);
  int lane = tid & 63, w = tid >> 6;
  if (lane == 0) red[w] = wq;
  __syncthreads();
  if (tid == 0) {
    float S = red[0] + red[1] + red[2] + red[3];
    float norm = sqrtf(S);
    sc = (norm == 0.f) ? 1.f : (1.f / norm);
  }
  __syncthreads();
  if (tid < 192) {
    float s = sc;
    float4 o = {e[0] * s, e[1] * s, e[2] * s, e[3] * s};
    *(float4*)(out + (size_t)v * D_ + tid * 4) = o;
  }
}

extern "C" void kernel_launch(void* const* d_in, const int* in_sizes, int n_in,
                              void* d_out, int out_size, void* d_ws,
                              size_t ws_size, hipStream_t stream) {
  (void)in_sizes; (void)n_in; (void)out_size; (void)ws_size;
  const float* h      = (const float*)d_in[0];
  const float* W_text = (const float*)d_in[1];
  const float* c_text = (const float*)d_in[2];
  const float* W_user = (const float*)d_in[3];
  const float* c_user = (const float*)d_in[4];
  const float* W_dst  = (const float*)d_in[5];
  const float* c_dst  = (const float*)d_in[6];
  const float* gamma  = (const float*)d_in[7];
  const float* beta   = (const float*)d_in[8];
  const float* W_lin  = (const float*)d_in[9];
  const float* b_lin  = (const float*)d_in[10];
  const int* src      = (const int*)d_in[11];
  const int* dst      = (const int*)d_in[12];
  const int* etype    = (const int*)d_in[13];
  const int* hete     = (const int*)d_in[14];
  float* out          = (float*)d_out;

  char* ws = (char*)d_ws;
  __hip_bfloat16* xb   = (__hip_bfloat16*)(ws + OFF_XB);
  __hip_bfloat16* WbT  = (__hip_bfloat16*)(ws + OFF_WBT);
  __hip_bfloat16* WlT  = (__hip_bfloat16*)(ws + OFF_WLT);
  __hip_bfloat16* nb16 = (__hip_bfloat16*)(ws + OFF_NB16);
  __hip_bfloat16* Y3   = (__hip_bfloat16*)(ws + OFF_Y3);   // [N][3][768]
  __hip_bfloat16* zbuf = (__hip_bfloat16*)(ws + OFF_ZB);
  __hip_bfloat16* n1c  = (__hip_bfloat16*)(ws + OFF_N1C);
  int* payload  = (int*)(ws + OFF_PAY);
  int* cnt4     = (int*)(ws + OFF_CNT);
  int* curH     = (int*)(ws + OFF_CURH);
  int* curU     = (int*)(ws + OFF_CURU);
  int* base     = (int*)(ws + OFF_BASE);
  int* blockcnt = (int*)(ws + OFF_BC);
  int* scanout  = (int*)(ws + OFF_SCAN);

  // one memset spans cnt4 + curH + curU (contiguous)
  hipMemsetAsync(cnt4, 0, 262144 + 65536 + 65536, stream);

  wprep_kernel<<<dim3(144, 11), 256, 0, stream>>>(W_text, W_user, W_dst,
                                                  W_lin, WbT, WlT);
  ln_kernel<<<N_, 256, 0, stream>>>(h, gamma, beta, xb);
  edge_a_kernel<<<E_ / 256, 256, 0, stream>>>(hete, dst, etype, blockcnt, cnt4);
  fused_scan_kernel<<<2, 1024, 0, stream>>>(blockcnt, scanout, cnt4, base);
  edge_bsort_kernel<<<E_ / 256, 256, 0, stream>>>(hete, dst, src, etype,
                                                  scanout, base, curH, curU,
                                                  payload);

  const dim3 ggrid(D_ / 128, N_ / 128, 3);

  // dst family: 3 basis GEMMs -> Y3 interleaved, then combine into nb16
  gemm_mfma_kernel<false, false><<<ggrid, 256, 0, stream>>>(
      xb, WbT + (size_t)6 * DSQ_, nullptr, Y3, N_, D_, D_, DSQ_, D3_, D_);
  combine_n2_kernel<<<(N_ * D_) / (256 * 8), 256, 0, stream>>>(Y3, c_dst,
                                                               cnt4, nb16);
  // text family (hete edges, segment 0)
  gemm_mfma_kernel<false, false><<<ggrid, 256, 0, stream>>>(
      xb, WbT, nullptr, Y3, N_, D_, D_, DSQ_, D3_, D_);
  gather_n1_kernel<true, 0><<<N_ / 4, 256, 0, stream>>>(
      Y3, c_text, base, curH, payload, n1c, nb16);
  // user family (homo edges, segment 1)
  gemm_mfma_kernel<false, false><<<ggrid, 256, 0, stream>>>(
      xb, WbT + (size_t)3 * DSQ_, nullptr, Y3, N_, D_, D_, DSQ_, D3_, D_);
  gather_n1_kernel<false, 1><<<N_ / 4, 256, 0, stream>>>(
      Y3, c_user, base, curH, payload, n1c, nb16);

  // z = relu(nb16 @ W_lin + b_lin) -> zbuf bf16 (reuses Y3), then norm
  gemm_mfma_kernel<true, true><<<dim3(D_ / 128, N_ / 128, 1), 256, 0, stream>>>(
      nb16, WlT, b_lin, zbuf, N_, D_, D2_, 0, D_, 0);
  norm_kernel<<<N_, 256, 0, stream>>>(zbuf, out);
}

// Round 17
// 440.050 us; speedup vs baseline: 1.1283x; 1.0374x over previous
//
#include <hip/hip_runtime.h>
#include <hip/hip_bf16.h>
#include <cstdint>

static constexpr int N_  = 16384;
static constexpr int E_  = 131072;
static constexpr int D_  = 768;
static constexpr int D2_ = 1536;
static constexpr int D3_ = 2304;   // interleaved Y row stride
static constexpr int DSQ_ = D_ * D_;

// ---------------- workspace layout (bytes), ~218.8 MB ----------------
static constexpr size_t OFF_XB   = 0;            // N*D bf16    = 25165824
static constexpr size_t OFF_WBT  = 25165824;     // 9*D*D bf16  = 10616832
static constexpr size_t OFF_WLT  = 39321600;     // D*2D bf16   = 2359296
static constexpr size_t OFF_NB16 = 41680896;     // N*2D bf16   = 50331648
static constexpr size_t OFF_Y3   = 92012544;     // N*3*D bf16  = 75497472 (interleaved)
static constexpr size_t OFF_ZB   = 92012544;     // N*D bf16 (reuses Y3)
static constexpr size_t OFF_N1C  = 192675840;    // N*D bf16 carry
static constexpr size_t OFF_PAY  = 217841664;    // E int32
static constexpr size_t OFF_CNT  = 218365952;    // N*4 int32   } one
static constexpr size_t OFF_CURH = 218628096;    // N int32     } memset
static constexpr size_t OFF_CURU = 218693632;    // N int32     } span
static constexpr size_t OFF_BASE = 218759168;    // (N+1) int32 (padded)
static constexpr size_t OFF_BC   = 218824736;    // 512 int32
static constexpr size_t OFF_SCAN = 218826784;    // 513 int32

typedef __attribute__((ext_vector_type(8))) short short8v;
typedef __attribute__((ext_vector_type(4))) float floatx4;
typedef __attribute__((ext_vector_type(16))) float floatx16;

__device__ __forceinline__ void gld16(const void* g, void* l) {
  __builtin_amdgcn_global_load_lds(
      (const __attribute__((address_space(1))) unsigned int*)g,
      (__attribute__((address_space(3))) unsigned int*)l, 16, 0, 0);
}

__device__ __forceinline__ float b2f(short u) {
  union { unsigned int i; float f; } x;
  x.i = ((unsigned int)(unsigned short)u) << 16;
  return x.f;
}

__device__ __forceinline__ float wave_sum(float v) {
#pragma unroll
  for (int o = 32; o; o >>= 1) v += __shfl_down(v, o, 64);
  return v;
}

// y in [0,9): WbT[fb][h][d] = W_f[b][d][h].  y in {9,10}: W_linT[h][k] =
// W_lin[k][h] (288 tiles split across two y rows). LDS 64x64 transpose.
__global__ __launch_bounds__(256) void wprep_kernel(
    const float* __restrict__ Wt, const float* __restrict__ Wu,
    const float* __restrict__ Wd, const float* __restrict__ Wl,
    __hip_bfloat16* __restrict__ WbT, __hip_bfloat16* __restrict__ WlT) {
  __shared__ float tile[64][65];
  int y = blockIdx.y;
  int tid = threadIdx.x;
  if (y < 9) {
    int f = y / 3, b = y % 3;
    const float* W = ((f == 0) ? Wt : ((f == 1) ? Wu : Wd)) + (size_t)b * DSQ_;
    int dt = (blockIdx.x / 12) * 64;
    int ht = (blockIdx.x % 12) * 64;
#pragma unroll
    for (int jj = 0; jj < 16; jj++) {
      int idx = jj * 256 + tid;
      int rr = idx >> 6, cc = idx & 63;
      tile[rr][cc] = W[(size_t)(dt + rr) * D_ + ht + cc];
    }
    __syncthreads();
#pragma unroll
    for (int jj = 0; jj < 16; jj++) {
      int idx = jj * 256 + tid;
      int hh = idx >> 6, dd = idx & 63;
      WbT[(size_t)y * DSQ_ + (size_t)(ht + hh) * D_ + dt + dd] =
          __float2bfloat16(tile[dd][hh]);
    }
  } else {
    int idx0 = (y - 9) * 144 + blockIdx.x;   // 0..287
    int kt = (idx0 % 24) * 64;
    int ht = (idx0 / 24) * 64;
#pragma unroll
    for (int jj = 0; jj < 16; jj++) {
      int idx = jj * 256 + tid;
      int rr = idx >> 6, cc = idx & 63;      // rr over k, cc over h
      tile[rr][cc] = Wl[(size_t)(kt + rr) * D_ + ht + cc];
    }
    __syncthreads();
#pragma unroll
    for (int jj = 0; jj < 16; jj++) {
      int idx = jj * 256 + tid;
      int hh = idx >> 6, dd = idx & 63;
      WlT[(size_t)(ht + hh) * D2_ + kt + dd] = __float2bfloat16(tile[dd][hh]);
    }
  }
}

// LayerNorm, float4 loads / short4 stores; 192 of 256 threads carry 4 elems.
__global__ __launch_bounds__(256) void ln_kernel(
    const float* __restrict__ h, const float* __restrict__ gamma,
    const float* __restrict__ beta, __hip_bfloat16* __restrict__ x) {
  int v = blockIdx.x, tid = threadIdx.x;
  float e[4] = {0.f, 0.f, 0.f, 0.f};
  float g[4], bta[4];
  if (tid < 192) {
    float4 a = *(const float4*)(h + (size_t)v * D_ + tid * 4);
    e[0] = a.x; e[1] = a.y; e[2] = a.z; e[3] = a.w;
    float4 gg = *(const float4*)(gamma + tid * 4);
    float4 bb = *(const float4*)(beta + tid * 4);
    g[0] = gg.x; g[1] = gg.y; g[2] = gg.z; g[3] = gg.w;
    bta[0] = bb.x; bta[1] = bb.y; bta[2] = bb.z; bta[3] = bb.w;
  }
  float s = e[0] + e[1] + e[2] + e[3];
  float q = e[0] * e[0] + e[1] * e[1] + e[2] * e[2] + e[3] * e[3];
  __shared__ float red[8];
  __shared__ float mv[2];
  float ws_ = wave_sum(s), wq = wave_sum(q);
  int lane = tid & 63, w = tid >> 6;
  if (lane == 0) { red[w] = ws_; red[4 + w] = wq; }
  __syncthreads();
  if (tid == 0) {
    float S = red[0] + red[1] + red[2] + red[3];
    float Q = red[4] + red[5] + red[6] + red[7];
    float mu = S * (1.0f / D_);
    float var = Q * (1.0f / D_) - mu * mu;
    mv[0] = mu;
    mv[1] = rsqrtf(var + 1e-5f);
  }
  __syncthreads();
  if (tid < 192) {
    float mu = mv[0], rstd = mv[1];
    __hip_bfloat16 o[4];
#pragma unroll
    for (int i = 0; i < 4; i++)
      o[i] = __float2bfloat16((e[i] - mu) * rstd * g[i] + bta[i]);
    *(short4*)(x + (size_t)v * D_ + tid * 4) = *(const short4*)o;
  }
}

// per-block hete counts + (dst,etype) histogram
__global__ __launch_bounds__(256) void edge_a_kernel(
    const int* __restrict__ hete, const int* __restrict__ dst,
    const int* __restrict__ etype, int* __restrict__ blockcnt,
    int* __restrict__ cnt4) {
  int j = blockIdx.x * 256 + threadIdx.x;
  int flag = hete[j] > 0;
  unsigned long long m = __ballot(flag);
  __shared__ int wsum[4];
  int lane = threadIdx.x & 63, w = threadIdx.x >> 6;
  if (lane == 0) wsum[w] = __popcll(m);
  __syncthreads();
  if (threadIdx.x == 0)
    blockcnt[blockIdx.x] = wsum[0] + wsum[1] + wsum[2] + wsum[3];
  atomicAdd(&cnt4[dst[j] * 4 + etype[j]], 1);
}

// block 0: exclusive scan over 512 blockcnt (+ total K at [512]).
// block 1: base[v] = exclusive prefix of deg[v]; base[N] = E.
__global__ __launch_bounds__(1024) void fused_scan_kernel(
    const int* __restrict__ blockcnt, int* __restrict__ scanout,
    const int* __restrict__ cnt4, int* __restrict__ base) {
  int t = threadIdx.x;
  if (blockIdx.x == 0) {
    __shared__ int s[1024];
    int v = (t < 512) ? blockcnt[t] : 0;
    s[t] = v;
    __syncthreads();
    for (int o = 1; o < 512; o <<= 1) {
      int add = (t >= o) ? s[t - o] : 0;
      __syncthreads();
      s[t] += add;
      __syncthreads();
    }
    if (t < 512) scanout[t] = s[t] - v;
    if (t == 511) scanout[512] = s[511];
  } else {
    __shared__ int s[1024];
    int loc[16];
    int sum = 0;
#pragma unroll
    for (int i = 0; i < 16; i++) {
      int v = t * 16 + i;
      int d = cnt4[v * 4] + cnt4[v * 4 + 1] + cnt4[v * 4 + 2] + cnt4[v * 4 + 3];
      loc[i] = sum;
      sum += d;
    }
    s[t] = sum;
    __syncthreads();
    for (int o = 1; o < 1024; o <<= 1) {
      int add = (t >= o) ? s[t - o] : 0;
      __syncthreads();
      s[t] += add;
      __syncthreads();
    }
    int pre = t ? s[t - 1] : 0;
#pragma unroll
    for (int i = 0; i < 16; i++) base[t * 16 + i] = pre + loc[i];
    if (t == 1023) base[N_] = s[1023];
  }
}

// Fused edge_b + edge_sort, two-ended bucket fill (hete ascending from
// base[v], homo descending from base[v+1]-1). payload = etype<<14 | src.
__global__ __launch_bounds__(256) void edge_bsort_kernel(
    const int* __restrict__ hete, const int* __restrict__ dst,
    const int* __restrict__ src, const int* __restrict__ etype,
    const int* __restrict__ scanout, const int* __restrict__ base,
    int* __restrict__ curH, int* __restrict__ curU,
    int* __restrict__ payload) {
  int j = blockIdx.x * 256 + threadIdx.x;
  int flag = hete[j] > 0;
  unsigned long long m = __ballot(flag);
  __shared__ int wsum[4];
  int lane = threadIdx.x & 63, w = threadIdx.x >> 6;
  if (lane == 0) wsum[w] = __popcll(m);
  __syncthreads();
  int wpre = 0;
#pragma unroll
  for (int i = 0; i < 4; i++) wpre += (i < w) ? wsum[i] : 0;
  int lpre = __popcll(m & ((1ull << lane) - 1ull));
  int hcum = scanout[blockIdx.x] + wpre + lpre;
  int K = scanout[512];
  int e = flag ? hcum : (K + j - hcum);
  int v = dst[e];
  int p;
  if (flag) p = base[v] + atomicAdd(&curH[v], 1);
  else      p = base[v + 1] - 1 - atomicAdd(&curU[v], 1);
  payload[p] = (etype[j] << 14) | src[j];
}

// Gather over one family segment. Y interleaved [v][3][768]: per edge ONE
// contiguous 4.6KB block (3 basis rows). Lane owns elems [lane*8,+8) and
// [512+lane*4,+4) of each row.
template <bool FIRST, int SEG>
__global__ __launch_bounds__(256) void gather_n1_kernel(
    const __hip_bfloat16* __restrict__ Y, const float* __restrict__ coeff,
    const int* __restrict__ base, const int* __restrict__ hcnt,
    const int* __restrict__ payload, __hip_bfloat16* __restrict__ n1c,
    __hip_bfloat16* __restrict__ nb16) {
  int wv = threadIdx.x >> 6, lane = threadIdx.x & 63;
  int v = blockIdx.x * 4 + wv;
  int bh = base[v] + hcnt[v];
  int lo = (SEG == 0) ? base[v] : bh;
  int hi = (SEG == 0) ? bh : base[v + 1];
  float cf[12];
#pragma unroll
  for (int i = 0; i < 12; i++) cf[i] = coeff[i];
  float acc[12];
  if (FIRST) {
#pragma unroll
    for (int i = 0; i < 12; i++) acc[i] = 0.f;
  } else {
    short8v a8 = *(const short8v*)(n1c + (size_t)v * D_ + lane * 8);
    short4  b4 = *(const short4*)(n1c + (size_t)v * D_ + 512 + lane * 4);
#pragma unroll
    for (int i = 0; i < 8; i++) acc[i] = b2f(a8[i]);
    acc[8] = b2f(b4.x); acc[9] = b2f(b4.y);
    acc[10] = b2f(b4.z); acc[11] = b2f(b4.w);
  }
  for (int idx = lo; idx < hi; ++idx) {
    int pl = payload[idx];
    int t = pl >> 14;
    float c0 = cf[t * 3], c1 = cf[t * 3 + 1], c2 = cf[t * 3 + 2];
    const __hip_bfloat16* r0 = Y + (size_t)(pl & 16383) * D3_;
    short8v a0 = *(const short8v*)(r0 + lane * 8);
    short8v a1 = *(const short8v*)(r0 + D_ + lane * 8);
    short8v a2 = *(const short8v*)(r0 + 2 * D_ + lane * 8);
    short4  b0v = *(const short4*)(r0 + 512 + lane * 4);
    short4  b1v = *(const short4*)(r0 + D_ + 512 + lane * 4);
    short4  b2v = *(const short4*)(r0 + 2 * D_ + 512 + lane * 4);
#pragma unroll
    for (int i = 0; i < 8; i++)
      acc[i] += fmaxf(c0 * b2f(a0[i]) + c1 * b2f(a1[i]) + c2 * b2f(a2[i]), 0.f);
    acc[8]  += fmaxf(c0 * b2f(b0v.x) + c1 * b2f(b1v.x) + c2 * b2f(b2v.x), 0.f);
    acc[9]  += fmaxf(c0 * b2f(b0v.y) + c1 * b2f(b1v.y) + c2 * b2f(b2v.y), 0.f);
    acc[10] += fmaxf(c0 * b2f(b0v.z) + c1 * b2f(b1v.z) + c2 * b2f(b2v.z), 0.f);
    acc[11] += fmaxf(c0 * b2f(b0v.w) + c1 * b2f(b1v.w) + c2 * b2f(b2v.w), 0.f);
  }
  __hip_bfloat16 o[12];
#pragma unroll
  for (int i = 0; i < 12; i++) o[i] = __float2bfloat16(acc[i]);
  if (FIRST) {
    *(short8v*)(n1c + (size_t)v * D_ + lane * 8) = *(const short8v*)o;
    *(short4*)(n1c + (size_t)v * D_ + 512 + lane * 4) = *(const short4*)(o + 8);
  } else {
    *(short8v*)(nb16 + (size_t)v * D2_ + lane * 8) = *(const short8v*)o;
    *(short4*)(nb16 + (size_t)v * D2_ + 512 + lane * 4) = *(const short4*)(o + 8);
  }
}

// nb16[v][768+k] = sum_t cnt4[v,t] * relu(sum_b cd[t,b] * Y[v][b][k])
__global__ __launch_bounds__(256) void combine_n2_kernel(
    const __hip_bfloat16* __restrict__ Y, const float* __restrict__ cd,
    const int* __restrict__ cnt4, __hip_bfloat16* __restrict__ nb16) {
  size_t i = ((size_t)blockIdx.x * 256 + threadIdx.x) * 8;
  int v = (int)(i / D_);
  int k = (int)(i % D_);
  const __hip_bfloat16* yr = Y + (size_t)v * D3_ + k;
  short8v y0 = *(const short8v*)(yr);
  short8v y1 = *(const short8v*)(yr + D_);
  short8v y2 = *(const short8v*)(yr + 2 * D_);
  float f0[8], f1[8], f2[8];
#pragma unroll
  for (int j = 0; j < 8; j++) {
    f0[j] = b2f(y0[j]); f1[j] = b2f(y1[j]); f2[j] = b2f(y2[j]);
  }
  float acc[8] = {0.f, 0.f, 0.f, 0.f, 0.f, 0.f, 0.f, 0.f};
#pragma unroll
  for (int t = 0; t < 4; t++) {
    float c = (float)cnt4[v * 4 + t];
    if (c != 0.f) {
      float d0 = cd[t * 3], d1 = cd[t * 3 + 1], d2 = cd[t * 3 + 2];
#pragma unroll
      for (int j = 0; j < 8; j++)
        acc[j] += c * fmaxf(d0 * f0[j] + d1 * f1[j] + d2 * f2[j], 0.f);
    }
  }
  __hip_bfloat16 o[8];
#pragma unroll
  for (int j = 0; j < 8; j++) o[j] = __float2bfloat16(acc[j]);
  *(short8v*)(nb16 + (size_t)v * D2_ + D_ + k) = *(const short8v*)o;
}

// C = op(A @ BT[z]^T (+bias)), op = relu iff RELU. bf16 out. z folded into
// XCD swizzle. C row stride ldC, z column offset zcol. 128x128 tile, BK=64,
// 4 waves (2x2), *** 32x32x16 bf16 MFMA *** (2x2 frags of 32x32 per wave,
// 4 k-steps per BK; 4 ds_reads + 4 MFMAs per k-step — half the MFMA issue
// count of the 16x16x32 version at +15% pipe rate). XOR-swizzled LDS,
// LDS-staged coalesced epilogue.
// A-frag: lane l holds A[l&31][(l>>5)*8 + j]. C/D: col=lane&31,
// row=(reg&3)+8*(reg>>2)+4*(lane>>5), reg in [0,16)  [guide m74/m101].
template <bool BIAS, bool RELU>
__global__ __launch_bounds__(256) void gemm_mfma_kernel(
    const __hip_bfloat16* __restrict__ A, const __hip_bfloat16* __restrict__ BT0,
    const float* __restrict__ bias, __hip_bfloat16* __restrict__ C0,
    int M, int N, int K, size_t strideB, int ldC, int zcol) {
  __shared__ char lds[32768];
  char* As = lds;
  char* Bs = lds + 16384;
  int tid = threadIdx.x;
  int lane = tid & 63;
  int wv = tid >> 6;
  int wr = wv >> 1, wc = wv & 1;
  int gx = gridDim.x, gz = gridDim.z;
  int nwg = gx * gridDim.y * gz;
  int id = (blockIdx.z * gridDim.y + blockIdx.y) * gx + blockIdx.x;
  int s = (id & 7) * (nwg >> 3) + (id >> 3);
  int bx = s % gx;
  int rem = s / gx;
  int z = rem % gz;
  int by = rem / gz;
  const __hip_bfloat16* BT = BT0 + (size_t)z * strideB;
  int row0 = by * 128, col0 = bx * 128;
  int r_ = tid >> 3;
  int s_ = tid & 7;

  floatx16 acc[2][2];
#pragma unroll
  for (int i = 0; i < 2; i++)
#pragma unroll
    for (int j = 0; j < 2; j++)
#pragma unroll
      for (int q = 0; q < 16; q++) acc[i][j][q] = 0.f;

  const int la = lane & 31;      // frag row/col within 32
  const int kh = lane >> 5;      // k-half selector

  for (int k0 = 0; k0 < K; k0 += 64) {
    __syncthreads();
#pragma unroll
    for (int is = 0; is < 4; is++) {
      int r = is * 32 + r_;
      int sp = s_ ^ (r & 7);
      gld16(A  + (size_t)(row0 + r) * K + k0 + sp * 8, As + is * 4096 + tid * 16);
      gld16(BT + (size_t)(col0 + r) * K + k0 + sp * 8, Bs + is * 4096 + tid * 16);
    }
    __syncthreads();
#pragma unroll
    for (int kk = 0; kk < 4; kk++) {       // 4 k-steps of K=16
      int p = kk * 2 + kh;                 // 16B slot within 64-K row
      short8v a0, a1, b0, b1;
      {
        int ra = wr * 64 + la;
        a0 = *(const short8v*)(As + ra * 128 + ((p ^ (ra & 7)) << 4));
        int ra1 = ra + 32;
        a1 = *(const short8v*)(As + ra1 * 128 + ((p ^ (ra1 & 7)) << 4));
        int rb = wc * 64 + la;
        b0 = *(const short8v*)(Bs + rb * 128 + ((p ^ (rb & 7)) << 4));
        int rb1 = rb + 32;
        b1 = *(const short8v*)(Bs + rb1 * 128 + ((p ^ (rb1 & 7)) << 4));
      }
      acc[0][0] = __builtin_amdgcn_mfma_f32_32x32x16_bf16(a0, b0, acc[0][0], 0, 0, 0);
      acc[0][1] = __builtin_amdgcn_mfma_f32_32x32x16_bf16(a0, b1, acc[0][1], 0, 0, 0);
      acc[1][0] = __builtin_amdgcn_mfma_f32_32x32x16_bf16(a1, b0, acc[1][0], 0, 0, 0);
      acc[1][1] = __builtin_amdgcn_mfma_f32_32x32x16_bf16(a1, b1, acc[1][1], 0, 0, 0);
    }
  }
  // ---- LDS-staged coalesced epilogue ----
  __syncthreads();
  char* cs = lds + wv * 8192;            // [64 r][64 c] bf16, slot rot (s+r)&7
#pragma unroll
  for (int fa = 0; fa < 2; fa++) {
#pragma unroll
    for (int fb = 0; fb < 2; fb++) {
      int c = fb * 32 + la;
      float bv = BIAS ? bias[col0 + wc * 64 + c] : 0.f;
#pragma unroll
      for (int reg = 0; reg < 16; reg++) {
        int r = fa * 32 + (reg & 3) + 8 * (reg >> 2) + 4 * kh;
        float v = acc[fa][fb][reg] + bv;
        if (RELU) v = fmaxf(v, 0.f);
        int byte = r * 128 + ((((c >> 3) + r) & 7) << 4) + ((c & 7) << 1);
        *(__hip_bfloat16*)(cs + byte) = __float2bfloat16(v);
      }
    }
  }
  __hip_bfloat16* C = C0 + (size_t)z * zcol;
#pragma unroll
  for (int i = 0; i < 8; i++) {
    int r = i * 8 + (lane >> 3);
    int s8 = lane & 7;
    int p = (s8 + r) & 7;
    short8v v = *(const short8v*)(cs + r * 128 + (p << 4));
    int grow = row0 + wr * 64 + r;
    int gcol = col0 + wc * 64 + s8 * 8;
    *(short8v*)(C + (size_t)grow * ldC + gcol) = v;
  }
}

// row L2-normalize: z bf16 -> out fp32.
__global__ __launch_bounds__(256) void norm_kernel(
    const __hip_bfloat16* __restrict__ z, float* __restrict__ out) {
  int v = blockIdx.x, tid = threadIdx.x;
  float e[4] = {0.f, 0.f, 0.f, 0.f};
  if (tid < 192) {
    short4 a = *(const short4*)(z + (size_t)v * D_ + tid * 4);
    e[0] = b2f(a.x); e[1] = b2f(a.y); e[2] = b2f(a.z); e[3] = b2f(a.w);
  }
  float q = e[0] * e[0] + e[1] * e[1] + e[2] * e[2] + e[3] * e[3];
  __shared__ float red[4];
  __shared__ float sc;
  float wq = wave_sum(q);
  int lane = tid & 63, w = tid >> 6;
  if (lane == 0) red[w] = wq;
  __syncthreads();
  if (tid == 0) {
    float S = red[0] + red[1] + red[2] + red[3];
    float norm = sqrtf(S);
    sc = (norm == 0.f) ? 1.f : (1.f / norm);
  }
  __syncthreads();
  if (tid < 192) {
    float s = sc;
    float4 o = {e[0] * s, e[1] * s, e[2] * s, e[3] * s};
    *(float4*)(out + (size_t)v * D_ + tid * 4) = o;
  }
}

extern "C" void kernel_launch(void* const* d_in, const int* in_sizes, int n_in,
                              void* d_out, int out_size, void* d_ws,
                              size_t ws_size, hipStream_t stream) {
  (void)in_sizes; (void)n_in; (void)out_size; (void)ws_size;
  const float* h      = (const float*)d_in[0];
  const float* W_text = (const float*)d_in[1];
  const float* c_text = (const float*)d_in[2];
  const float* W_user = (const float*)d_in[3];
  const float* c_user = (const float*)d_in[4];
  const float* W_dst  = (const float*)d_in[5];
  const float* c_dst  = (const float*)d_in[6];
  const float* gamma  = (const float*)d_in[7];
  const float* beta   = (const float*)d_in[8];
  const float* W_lin  = (const float*)d_in[9];
  const float* b_lin  = (const float*)d_in[10];
  const int* src      = (const int*)d_in[11];
  const int* dst      = (const int*)d_in[12];
  const int* etype    = (const int*)d_in[13];
  const int* hete     = (const int*)d_in[14];
  float* out          = (float*)d_out;

  char* ws = (char*)d_ws;
  __hip_bfloat16* xb   = (__hip_bfloat16*)(ws + OFF_XB);
  __hip_bfloat16* WbT  = (__hip_bfloat16*)(ws + OFF_WBT);
  __hip_bfloat16* WlT  = (__hip_bfloat16*)(ws + OFF_WLT);
  __hip_bfloat16* nb16 = (__hip_bfloat16*)(ws + OFF_NB16);
  __hip_bfloat16* Y3   = (__hip_bfloat16*)(ws + OFF_Y3);   // [N][3][768]
  __hip_bfloat16* zbuf = (__hip_bfloat16*)(ws + OFF_ZB);
  __hip_bfloat16* n1c  = (__hip_bfloat16*)(ws + OFF_N1C);
  int* payload  = (int*)(ws + OFF_PAY);
  int* cnt4     = (int*)(ws + OFF_CNT);
  int* curH     = (int*)(ws + OFF_CURH);
  int* curU     = (int*)(ws + OFF_CURU);
  int* base     = (int*)(ws + OFF_BASE);
  int* blockcnt = (int*)(ws + OFF_BC);
  int* scanout  = (int*)(ws + OFF_SCAN);

  // one memset spans cnt4 + curH + curU (contiguous)
  hipMemsetAsync(cnt4, 0, 262144 + 65536 + 65536, stream);

  wprep_kernel<<<dim3(144, 11), 256, 0, stream>>>(W_text, W_user, W_dst,
                                                  W_lin, WbT, WlT);
  ln_kernel<<<N_, 256, 0, stream>>>(h, gamma, beta, xb);
  edge_a_kernel<<<E_ / 256, 256, 0, stream>>>(hete, dst, etype, blockcnt, cnt4);
  fused_scan_kernel<<<2, 1024, 0, stream>>>(blockcnt, scanout, cnt4, base);
  edge_bsort_kernel<<<E_ / 256, 256, 0, stream>>>(hete, dst, src, etype,
                                                  scanout, base, curH, curU,
                                                  payload);

  const dim3 ggrid(D_ / 128, N_ / 128, 3);

  // dst family: 3 basis GEMMs -> Y3 interleaved, then combine into nb16
  gemm_mfma_kernel<false, false><<<ggrid, 256, 0, stream>>>(
      xb, WbT + (size_t)6 * DSQ_, nullptr, Y3, N_, D_, D_, DSQ_, D3_, D_);
  combine_n2_kernel<<<(N_ * D_) / (256 * 8), 256, 0, stream>>>(Y3, c_dst,
                                                               cnt4, nb16);
  // text family (hete edges, segment 0)
  gemm_mfma_kernel<false, false><<<ggrid, 256, 0, stream>>>(
      xb, WbT, nullptr, Y3, N_, D_, D_, DSQ_, D3_, D_);
  gather_n1_kernel<true, 0><<<N_ / 4, 256, 0, stream>>>(
      Y3, c_text, base, curH, payload, n1c, nb16);
  // user family (homo edges, segment 1)
  gemm_mfma_kernel<false, false><<<ggrid, 256, 0, stream>>>(
      xb, WbT + (size_t)3 * DSQ_, nullptr, Y3, N_, D_, D_, DSQ_, D3_, D_);
  gather_n1_kernel<false, 1><<<N_ / 4, 256, 0, stream>>>(
      Y3, c_user, base, curH, payload, n1c, nb16);

  // z = relu(nb16 @ W_lin + b_lin) -> zbuf bf16 (reuses Y3), then norm
  gemm_mfma_kernel<true, true><<<dim3(D_ / 128, N_ / 128, 1), 256, 0, stream>>>(
      nb16, WlT, b_lin, zbuf, N_, D_, D2_, 0, D_, 0);
  norm_kernel<<<N_, 256, 0, stream>>>(zbuf, out);
}

// Round 18
// 434.718 us; speedup vs baseline: 1.1421x; 1.0123x over previous
//
#include <hip/hip_runtime.h>
#include <hip/hip_bf16.h>
#include <cstdint>

static constexpr int N_  = 16384;
static constexpr int E_  = 131072;
static constexpr int D_  = 768;
static constexpr int D2_ = 1536;
static constexpr int D3_ = 2304;   // interleaved Y row stride
static constexpr int DSQ_ = D_ * D_;

// ---------------- workspace layout (bytes), ~218.8 MB ----------------
static constexpr size_t OFF_XB   = 0;            // N*D bf16    = 25165824
static constexpr size_t OFF_WBT  = 25165824;     // 9*D*D bf16  = 10616832
static constexpr size_t OFF_WLT  = 39321600;     // D*2D bf16   = 2359296
static constexpr size_t OFF_NB16 = 41680896;     // N*2D bf16   = 50331648
static constexpr size_t OFF_Y3   = 92012544;     // N*3*D bf16  = 75497472 (interleaved)
static constexpr size_t OFF_ZB   = 92012544;     // N*D bf16 (reuses Y3)
static constexpr size_t OFF_N1C  = 192675840;    // N*D bf16 carry
static constexpr size_t OFF_PAY  = 217841664;    // E int32
static constexpr size_t OFF_CNT  = 218365952;    // N*4 int32   } one
static constexpr size_t OFF_CURH = 218628096;    // N int32     } memset
static constexpr size_t OFF_CURU = 218693632;    // N int32     } span
static constexpr size_t OFF_BASE = 218759168;    // (N+1) int32 (padded)
static constexpr size_t OFF_BC   = 218824736;    // 512 int32
static constexpr size_t OFF_SCAN = 218826784;    // 513 int32

typedef __attribute__((ext_vector_type(8))) short short8v;
typedef __attribute__((ext_vector_type(4))) float floatx4;
typedef __attribute__((ext_vector_type(16))) float floatx16;

__device__ __forceinline__ void gld16(const void* g, void* l) {
  __builtin_amdgcn_global_load_lds(
      (const __attribute__((address_space(1))) unsigned int*)g,
      (__attribute__((address_space(3))) unsigned int*)l, 16, 0, 0);
}

__device__ __forceinline__ float b2f(short u) {
  union { unsigned int i; float f; } x;
  x.i = ((unsigned int)(unsigned short)u) << 16;
  return x.f;
}

__device__ __forceinline__ float wave_sum(float v) {
#pragma unroll
  for (int o = 32; o; o >>= 1) v += __shfl_down(v, o, 64);
  return v;
}

// One launch, three independent jobs by block range:
//  [0,1584): weight transpose (9 basis mats + W_lin over 2x144 tiles)
//  [1584, 1584+16384): LayerNorm rows
//  [1584+16384, +512): edge histogram + per-block hete counts
__global__ __launch_bounds__(256) void mega_prep_kernel(
    const float* __restrict__ Wt, const float* __restrict__ Wu,
    const float* __restrict__ Wd, const float* __restrict__ Wl,
    __hip_bfloat16* __restrict__ WbT, __hip_bfloat16* __restrict__ WlT,
    const float* __restrict__ h, const float* __restrict__ gamma,
    const float* __restrict__ beta, __hip_bfloat16* __restrict__ x,
    const int* __restrict__ hete, const int* __restrict__ dst,
    const int* __restrict__ etype, int* __restrict__ blockcnt,
    int* __restrict__ cnt4) {
  __shared__ char smem[64 * 65 * 4];
  int bid = blockIdx.x;
  int tid = threadIdx.x;
  if (bid < 1584) {
    float (*tile)[65] = (float(*)[65])smem;
    int y = bid / 144, bx = bid % 144;
    if (y < 9) {
      int f = y / 3, b = y % 3;
      const float* W = ((f == 0) ? Wt : ((f == 1) ? Wu : Wd)) + (size_t)b * DSQ_;
      int dt = (bx / 12) * 64;
      int ht = (bx % 12) * 64;
#pragma unroll
      for (int jj = 0; jj < 16; jj++) {
        int idx = jj * 256 + tid;
        int rr = idx >> 6, cc = idx & 63;
        tile[rr][cc] = W[(size_t)(dt + rr) * D_ + ht + cc];
      }
      __syncthreads();
#pragma unroll
      for (int jj = 0; jj < 16; jj++) {
        int idx = jj * 256 + tid;
        int hh = idx >> 6, dd = idx & 63;
        WbT[(size_t)y * DSQ_ + (size_t)(ht + hh) * D_ + dt + dd] =
            __float2bfloat16(tile[dd][hh]);
      }
    } else {
      int idx0 = (y - 9) * 144 + bx;   // 0..287
      int kt = (idx0 % 24) * 64;
      int ht = (idx0 / 24) * 64;
#pragma unroll
      for (int jj = 0; jj < 16; jj++) {
        int idx = jj * 256 + tid;
        int rr = idx >> 6, cc = idx & 63;      // rr over k, cc over h
        tile[rr][cc] = Wl[(size_t)(kt + rr) * D_ + ht + cc];
      }
      __syncthreads();
#pragma unroll
      for (int jj = 0; jj < 16; jj++) {
        int idx = jj * 256 + tid;
        int hh = idx >> 6, dd = idx & 63;
        WlT[(size_t)(ht + hh) * D2_ + kt + dd] = __float2bfloat16(tile[dd][hh]);
      }
    }
  } else if (bid < 1584 + N_) {
    int v = bid - 1584;
    float* red = (float*)smem;       // [8]
    float* mv = red + 8;             // [2]
    float e[4] = {0.f, 0.f, 0.f, 0.f};
    float g[4], bta[4];
    if (tid < 192) {
      float4 a = *(const float4*)(h + (size_t)v * D_ + tid * 4);
      e[0] = a.x; e[1] = a.y; e[2] = a.z; e[3] = a.w;
      float4 gg = *(const float4*)(gamma + tid * 4);
      float4 bb = *(const float4*)(beta + tid * 4);
      g[0] = gg.x; g[1] = gg.y; g[2] = gg.z; g[3] = gg.w;
      bta[0] = bb.x; bta[1] = bb.y; bta[2] = bb.z; bta[3] = bb.w;
    }
    float s = e[0] + e[1] + e[2] + e[3];
    float q = e[0] * e[0] + e[1] * e[1] + e[2] * e[2] + e[3] * e[3];
    float ws_ = wave_sum(s), wq = wave_sum(q);
    int lane = tid & 63, w = tid >> 6;
    if (lane == 0) { red[w] = ws_; red[4 + w] = wq; }
    __syncthreads();
    if (tid == 0) {
      float S = red[0] + red[1] + red[2] + red[3];
      float Q = red[4] + red[5] + red[6] + red[7];
      float mu = S * (1.0f / D_);
      float var = Q * (1.0f / D_) - mu * mu;
      mv[0] = mu;
      mv[1] = rsqrtf(var + 1e-5f);
    }
    __syncthreads();
    if (tid < 192) {
      float mu = mv[0], rstd = mv[1];
      __hip_bfloat16 o[4];
#pragma unroll
      for (int i = 0; i < 4; i++)
        o[i] = __float2bfloat16((e[i] - mu) * rstd * g[i] + bta[i]);
      *(short4*)(x + (size_t)v * D_ + tid * 4) = *(const short4*)o;
    }
  } else {
    int blk = bid - 1584 - N_;       // 0..511
    int* wsum = (int*)smem;          // [4]
    int j = blk * 256 + tid;
    int flag = hete[j] > 0;
    unsigned long long m = __ballot(flag);
    int lane = tid & 63, w = tid >> 6;
    if (lane == 0) wsum[w] = __popcll(m);
    __syncthreads();
    if (tid == 0)
      blockcnt[blk] = wsum[0] + wsum[1] + wsum[2] + wsum[3];
    atomicAdd(&cnt4[dst[j] * 4 + etype[j]], 1);
  }
}

// block 0: exclusive scan over 512 blockcnt (+ total K at [512]).
// block 1: base[v] = exclusive prefix of deg[v]; base[N] = E.
__global__ __launch_bounds__(1024) void fused_scan_kernel(
    const int* __restrict__ blockcnt, int* __restrict__ scanout,
    const int* __restrict__ cnt4, int* __restrict__ base) {
  int t = threadIdx.x;
  if (blockIdx.x == 0) {
    __shared__ int s[1024];
    int v = (t < 512) ? blockcnt[t] : 0;
    s[t] = v;
    __syncthreads();
    for (int o = 1; o < 512; o <<= 1) {
      int add = (t >= o) ? s[t - o] : 0;
      __syncthreads();
      s[t] += add;
      __syncthreads();
    }
    if (t < 512) scanout[t] = s[t] - v;
    if (t == 511) scanout[512] = s[511];
  } else {
    __shared__ int s[1024];
    int loc[16];
    int sum = 0;
#pragma unroll
    for (int i = 0; i < 16; i++) {
      int v = t * 16 + i;
      int d = cnt4[v * 4] + cnt4[v * 4 + 1] + cnt4[v * 4 + 2] + cnt4[v * 4 + 3];
      loc[i] = sum;
      sum += d;
    }
    s[t] = sum;
    __syncthreads();
    for (int o = 1; o < 1024; o <<= 1) {
      int add = (t >= o) ? s[t - o] : 0;
      __syncthreads();
      s[t] += add;
      __syncthreads();
    }
    int pre = t ? s[t - 1] : 0;
#pragma unroll
    for (int i = 0; i < 16; i++) base[t * 16 + i] = pre + loc[i];
    if (t == 1023) base[N_] = s[1023];
  }
}

// Fused edge_b + edge_sort, two-ended bucket fill (hete ascending from
// base[v], homo descending from base[v+1]-1). payload = etype<<14 | src.
__global__ __launch_bounds__(256) void edge_bsort_kernel(
    const int* __restrict__ hete, const int* __restrict__ dst,
    const int* __restrict__ src, const int* __restrict__ etype,
    const int* __restrict__ scanout, const int* __restrict__ base,
    int* __restrict__ curH, int* __restrict__ curU,
    int* __restrict__ payload) {
  int j = blockIdx.x * 256 + threadIdx.x;
  int flag = hete[j] > 0;
  unsigned long long m = __ballot(flag);
  __shared__ int wsum[4];
  int lane = threadIdx.x & 63, w = threadIdx.x >> 6;
  if (lane == 0) wsum[w] = __popcll(m);
  __syncthreads();
  int wpre = 0;
#pragma unroll
  for (int i = 0; i < 4; i++) wpre += (i < w) ? wsum[i] : 0;
  int lpre = __popcll(m & ((1ull << lane) - 1ull));
  int hcum = scanout[blockIdx.x] + wpre + lpre;
  int K = scanout[512];
  int e = flag ? hcum : (K + j - hcum);
  int v = dst[e];
  int p;
  if (flag) p = base[v] + atomicAdd(&curH[v], 1);
  else      p = base[v + 1] - 1 - atomicAdd(&curU[v], 1);
  payload[p] = (etype[j] << 14) | src[j];
}

// Gather over one family segment. Y interleaved [v][3][768]: per edge ONE
// contiguous 4.6KB block (3 basis rows). Lane owns elems [lane*8,+8) and
// [512+lane*4,+4) of each row.
template <bool FIRST, int SEG>
__global__ __launch_bounds__(256) void gather_n1_kernel(
    const __hip_bfloat16* __restrict__ Y, const float* __restrict__ coeff,
    const int* __restrict__ base, const int* __restrict__ hcnt,
    const int* __restrict__ payload, __hip_bfloat16* __restrict__ n1c,
    __hip_bfloat16* __restrict__ nb16) {
  int wv = threadIdx.x >> 6, lane = threadIdx.x & 63;
  int v = blockIdx.x * 4 + wv;
  int bh = base[v] + hcnt[v];
  int lo = (SEG == 0) ? base[v] : bh;
  int hi = (SEG == 0) ? bh : base[v + 1];
  float cf[12];
#pragma unroll
  for (int i = 0; i < 12; i++) cf[i] = coeff[i];
  float acc[12];
  if (FIRST) {
#pragma unroll
    for (int i = 0; i < 12; i++) acc[i] = 0.f;
  } else {
    short8v a8 = *(const short8v*)(n1c + (size_t)v * D_ + lane * 8);
    short4  b4 = *(const short4*)(n1c + (size_t)v * D_ + 512 + lane * 4);
#pragma unroll
    for (int i = 0; i < 8; i++) acc[i] = b2f(a8[i]);
    acc[8] = b2f(b4.x); acc[9] = b2f(b4.y);
    acc[10] = b2f(b4.z); acc[11] = b2f(b4.w);
  }
  for (int idx = lo; idx < hi; ++idx) {
    int pl = payload[idx];
    int t = pl >> 14;
    float c0 = cf[t * 3], c1 = cf[t * 3 + 1], c2 = cf[t * 3 + 2];
    const __hip_bfloat16* r0 = Y + (size_t)(pl & 16383) * D3_;
    short8v a0 = *(const short8v*)(r0 + lane * 8);
    short8v a1 = *(const short8v*)(r0 + D_ + lane * 8);
    short8v a2 = *(const short8v*)(r0 + 2 * D_ + lane * 8);
    short4  b0v = *(const short4*)(r0 + 512 + lane * 4);
    short4  b1v = *(const short4*)(r0 + D_ + 512 + lane * 4);
    short4  b2v = *(const short4*)(r0 + 2 * D_ + 512 + lane * 4);
#pragma unroll
    for (int i = 0; i < 8; i++)
      acc[i] += fmaxf(c0 * b2f(a0[i]) + c1 * b2f(a1[i]) + c2 * b2f(a2[i]), 0.f);
    acc[8]  += fmaxf(c0 * b2f(b0v.x) + c1 * b2f(b1v.x) + c2 * b2f(b2v.x), 0.f);
    acc[9]  += fmaxf(c0 * b2f(b0v.y) + c1 * b2f(b1v.y) + c2 * b2f(b2v.y), 0.f);
    acc[10] += fmaxf(c0 * b2f(b0v.z) + c1 * b2f(b1v.z) + c2 * b2f(b2v.z), 0.f);
    acc[11] += fmaxf(c0 * b2f(b0v.w) + c1 * b2f(b1v.w) + c2 * b2f(b2v.w), 0.f);
  }
  __hip_bfloat16 o[12];
#pragma unroll
  for (int i = 0; i < 12; i++) o[i] = __float2bfloat16(acc[i]);
  if (FIRST) {
    *(short8v*)(n1c + (size_t)v * D_ + lane * 8) = *(const short8v*)o;
    *(short4*)(n1c + (size_t)v * D_ + 512 + lane * 4) = *(const short4*)(o + 8);
  } else {
    *(short8v*)(nb16 + (size_t)v * D2_ + lane * 8) = *(const short8v*)o;
    *(short4*)(nb16 + (size_t)v * D2_ + 512 + lane * 4) = *(const short4*)(o + 8);
  }
}

// nb16[v][768+k] = sum_t cnt4[v,t] * relu(sum_b cd[t,b] * Y[v][b][k])
__global__ __launch_bounds__(256) void combine_n2_kernel(
    const __hip_bfloat16* __restrict__ Y, const float* __restrict__ cd,
    const int* __restrict__ cnt4, __hip_bfloat16* __restrict__ nb16) {
  size_t i = ((size_t)blockIdx.x * 256 + threadIdx.x) * 8;
  int v = (int)(i / D_);
  int k = (int)(i % D_);
  const __hip_bfloat16* yr = Y + (size_t)v * D3_ + k;
  short8v y0 = *(const short8v*)(yr);
  short8v y1 = *(const short8v*)(yr + D_);
  short8v y2 = *(const short8v*)(yr + 2 * D_);
  float f0[8], f1[8], f2[8];
#pragma unroll
  for (int j = 0; j < 8; j++) {
    f0[j] = b2f(y0[j]); f1[j] = b2f(y1[j]); f2[j] = b2f(y2[j]);
  }
  float acc[8] = {0.f, 0.f, 0.f, 0.f, 0.f, 0.f, 0.f, 0.f};
#pragma unroll
  for (int t = 0; t < 4; t++) {
    float c = (float)cnt4[v * 4 + t];
    if (c != 0.f) {
      float d0 = cd[t * 3], d1 = cd[t * 3 + 1], d2 = cd[t * 3 + 2];
#pragma unroll
      for (int j = 0; j < 8; j++)
        acc[j] += c * fmaxf(d0 * f0[j] + d1 * f1[j] + d2 * f2[j], 0.f);
    }
  }
  __hip_bfloat16 o[8];
#pragma unroll
  for (int j = 0; j < 8; j++) o[j] = __float2bfloat16(acc[j]);
  *(short8v*)(nb16 + (size_t)v * D2_ + D_ + k) = *(const short8v*)o;
}

// C = op(A @ BT[z]^T (+bias)), op = relu iff RELU. bf16 out. z folded into
// XCD swizzle. C row stride ldC, z column offset zcol. 128x128 tile, BK=64,
// 4 waves (2x2), 32x32x16 bf16 MFMA (2x2 frags of 32x32 per wave, 4 k-steps
// per BK). XOR-swizzled LDS, LDS-staged coalesced epilogue.
// A-frag: lane l holds A[l&31][(l>>5)*8 + j]. C/D: col=lane&31,
// row=(reg&3)+8*(reg>>2)+4*(lane>>5), reg in [0,16)  [guide m74/m101].
template <bool BIAS, bool RELU>
__global__ __launch_bounds__(256) void gemm_mfma_kernel(
    const __hip_bfloat16* __restrict__ A, const __hip_bfloat16* __restrict__ BT0,
    const float* __restrict__ bias, __hip_bfloat16* __restrict__ C0,
    int M, int N, int K, size_t strideB, int ldC, int zcol) {
  __shared__ char lds[32768];
  char* As = lds;
  char* Bs = lds + 16384;
  int tid = threadIdx.x;
  int lane = tid & 63;
  int wv = tid >> 6;
  int wr = wv >> 1, wc = wv & 1;
  int gx = gridDim.x, gz = gridDim.z;
  int nwg = gx * gridDim.y * gz;
  int id = (blockIdx.z * gridDim.y + blockIdx.y) * gx + blockIdx.x;
  int s = (id & 7) * (nwg >> 3) + (id >> 3);
  int bx = s % gx;
  int rem = s / gx;
  int z = rem % gz;
  int by = rem / gz;
  const __hip_bfloat16* BT = BT0 + (size_t)z * strideB;
  int row0 = by * 128, col0 = bx * 128;
  int r_ = tid >> 3;
  int s_ = tid & 7;

  floatx16 acc[2][2];
#pragma unroll
  for (int i = 0; i < 2; i++)
#pragma unroll
    for (int j = 0; j < 2; j++)
#pragma unroll
      for (int q = 0; q < 16; q++) acc[i][j][q] = 0.f;

  const int la = lane & 31;      // frag row/col within 32
  const int kh = lane >> 5;      // k-half selector

  for (int k0 = 0; k0 < K; k0 += 64) {
    __syncthreads();
#pragma unroll
    for (int is = 0; is < 4; is++) {
      int r = is * 32 + r_;
      int sp = s_ ^ (r & 7);
      gld16(A  + (size_t)(row0 + r) * K + k0 + sp * 8, As + is * 4096 + tid * 16);
      gld16(BT + (size_t)(col0 + r) * K + k0 + sp * 8, Bs + is * 4096 + tid * 16);
    }
    __syncthreads();
#pragma unroll
    for (int kk = 0; kk < 4; kk++) {       // 4 k-steps of K=16
      int p = kk * 2 + kh;                 // 16B slot within 64-K row
      short8v a0, a1, b0, b1;
      {
        int ra = wr * 64 + la;
        a0 = *(const short8v*)(As + ra * 128 + ((p ^ (ra & 7)) << 4));
        int ra1 = ra + 32;
        a1 = *(const short8v*)(As + ra1 * 128 + ((p ^ (ra1 & 7)) << 4));
        int rb = wc * 64 + la;
        b0 = *(const short8v*)(Bs + rb * 128 + ((p ^ (rb & 7)) << 4));
        int rb1 = rb + 32;
        b1 = *(const short8v*)(Bs + rb1 * 128 + ((p ^ (rb1 & 7)) << 4));
      }
      acc[0][0] = __builtin_amdgcn_mfma_f32_32x32x16_bf16(a0, b0, acc[0][0], 0, 0, 0);
      acc[0][1] = __builtin_amdgcn_mfma_f32_32x32x16_bf16(a0, b1, acc[0][1], 0, 0, 0);
      acc[1][0] = __builtin_amdgcn_mfma_f32_32x32x16_bf16(a1, b0, acc[1][0], 0, 0, 0);
      acc[1][1] = __builtin_amdgcn_mfma_f32_32x32x16_bf16(a1, b1, acc[1][1], 0, 0, 0);
    }
  }
  // ---- LDS-staged coalesced epilogue ----
  __syncthreads();
  char* cs = lds + wv * 8192;            // [64 r][64 c] bf16, slot rot (s+r)&7
#pragma unroll
  for (int fa = 0; fa < 2; fa++) {
#pragma unroll
    for (int fb = 0; fb < 2; fb++) {
      int c = fb * 32 + la;
      float bv = BIAS ? bias[col0 + wc * 64 + c] : 0.f;
#pragma unroll
      for (int reg = 0; reg < 16; reg++) {
        int r = fa * 32 + (reg & 3) + 8 * (reg >> 2) + 4 * kh;
        float v = acc[fa][fb][reg] + bv;
        if (RELU) v = fmaxf(v, 0.f);
        int byte = r * 128 + ((((c >> 3) + r) & 7) << 4) + ((c & 7) << 1);
        *(__hip_bfloat16*)(cs + byte) = __float2bfloat16(v);
      }
    }
  }
  __hip_bfloat16* C = C0 + (size_t)z * zcol;
#pragma unroll
  for (int i = 0; i < 8; i++) {
    int r = i * 8 + (lane >> 3);
    int s8 = lane & 7;
    int p = (s8 + r) & 7;
    short8v v = *(const short8v*)(cs + r * 128 + (p << 4));
    int grow = row0 + wr * 64 + r;
    int gcol = col0 + wc * 64 + s8 * 8;
    *(short8v*)(C + (size_t)grow * ldC + gcol) = v;
  }
}

// row L2-normalize: z bf16 -> out fp32.
__global__ __launch_bounds__(256) void norm_kernel(
    const __hip_bfloat16* __restrict__ z, float* __restrict__ out) {
  int v = blockIdx.x, tid = threadIdx.x;
  float e[4] = {0.f, 0.f, 0.f, 0.f};
  if (tid < 192) {
    short4 a = *(const short4*)(z + (size_t)v * D_ + tid * 4);
    e[0] = b2f(a.x); e[1] = b2f(a.y); e[2] = b2f(a.z); e[3] = b2f(a.w);
  }
  float q = e[0] * e[0] + e[1] * e[1] + e[2] * e[2] + e[3] * e[3];
  __shared__ float red[4];
  __shared__ float sc;
  float wq = wave_sum(q);
  int lane = tid & 63, w = tid >> 6;
  if (lane == 0) red[w] = wq;
  __syncthreads();
  if (tid == 0) {
    float S = red[0] + red[1] + red[2] + red[3];
    float norm = sqrtf(S);
    sc = (norm == 0.f) ? 1.f : (1.f / norm);
  }
  __syncthreads();
  if (tid < 192) {
    float s = sc;
    float4 o = {e[0] * s, e[1] * s, e[2] * s, e[3] * s};
    *(float4*)(out + (size_t)v * D_ + tid * 4) = o;
  }
}

extern "C" void kernel_launch(void* const* d_in, const int* in_sizes, int n_in,
                              void* d_out, int out_size, void* d_ws,
                              size_t ws_size, hipStream_t stream) {
  (void)in_sizes; (void)n_in; (void)out_size; (void)ws_size;
  const float* h      = (const float*)d_in[0];
  const float* W_text = (const float*)d_in[1];
  const float* c_text = (const float*)d_in[2];
  const float* W_user = (const float*)d_in[3];
  const float* c_user = (const float*)d_in[4];
  const float* W_dst  = (const float*)d_in[5];
  const float* c_dst  = (const float*)d_in[6];
  const float* gamma  = (const float*)d_in[7];
  const float* beta   = (const float*)d_in[8];
  const float* W_lin  = (const float*)d_in[9];
  const float* b_lin  = (const float*)d_in[10];
  const int* src      = (const int*)d_in[11];
  const int* dst      = (const int*)d_in[12];
  const int* etype    = (const int*)d_in[13];
  const int* hete     = (const int*)d_in[14];
  float* out          = (float*)d_out;

  char* ws = (char*)d_ws;
  __hip_bfloat16* xb   = (__hip_bfloat16*)(ws + OFF_XB);
  __hip_bfloat16* WbT  = (__hip_bfloat16*)(ws + OFF_WBT);
  __hip_bfloat16* WlT  = (__hip_bfloat16*)(ws + OFF_WLT);
  __hip_bfloat16* nb16 = (__hip_bfloat16*)(ws + OFF_NB16);
  __hip_bfloat16* Y3   = (__hip_bfloat16*)(ws + OFF_Y3);   // [N][3][768]
  __hip_bfloat16* zbuf = (__hip_bfloat16*)(ws + OFF_ZB);
  __hip_bfloat16* n1c  = (__hip_bfloat16*)(ws + OFF_N1C);
  int* payload  = (int*)(ws + OFF_PAY);
  int* cnt4     = (int*)(ws + OFF_CNT);
  int* curH     = (int*)(ws + OFF_CURH);
  int* curU     = (int*)(ws + OFF_CURU);
  int* base     = (int*)(ws + OFF_BASE);
  int* blockcnt = (int*)(ws + OFF_BC);
  int* scanout  = (int*)(ws + OFF_SCAN);

  // one memset spans cnt4 + curH + curU (contiguous)
  hipMemsetAsync(cnt4, 0, 262144 + 65536 + 65536, stream);

  mega_prep_kernel<<<1584 + N_ + 512, 256, 0, stream>>>(
      W_text, W_user, W_dst, W_lin, WbT, WlT, h, gamma, beta, xb, hete, dst,
      etype, blockcnt, cnt4);
  fused_scan_kernel<<<2, 1024, 0, stream>>>(blockcnt, scanout, cnt4, base);
  edge_bsort_kernel<<<E_ / 256, 256, 0, stream>>>(hete, dst, src, etype,
                                                  scanout, base, curH, curU,
                                                  payload);

  const dim3 ggrid(D_ / 128, N_ / 128, 3);

  // dst family: 3 basis GEMMs -> Y3 interleaved, then combine into nb16
  gemm_mfma_kernel<false, false><<<ggrid, 256, 0, stream>>>(
      xb, WbT + (size_t)6 * DSQ_, nullptr, Y3, N_, D_, D_, DSQ_, D3_, D_);
  combine_n2_kernel<<<(N_ * D_) / (256 * 8), 256, 0, stream>>>(Y3, c_dst,
                                                               cnt4, nb16);
  // text family (hete edges, segment 0)
  gemm_mfma_kernel<false, false><<<ggrid, 256, 0, stream>>>(
      xb, WbT, nullptr, Y3, N_, D_, D_, DSQ_, D3_, D_);
  gather_n1_kernel<true, 0><<<N_ / 4, 256, 0, stream>>>(
      Y3, c_text, base, curH, payload, n1c, nb16);
  // user family (homo edges, segment 1)
  gemm_mfma_kernel<false, false><<<ggrid, 256, 0, stream>>>(
      xb, WbT + (size_t)3 * DSQ_, nullptr, Y3, N_, D_, D_, DSQ_, D3_, D_);
  gather_n1_kernel<false, 1><<<N_ / 4, 256, 0, stream>>>(
      Y3, c_user, base, curH, payload, n1c, nb16);

  // z = relu(nb16 @ W_lin + b_lin) -> zbuf bf16 (reuses Y3), then norm
  gemm_mfma_kernel<true, true><<<dim3(D_ / 128, N_ / 128, 1), 256, 0, stream>>>(
      nb16, WlT, b_lin, zbuf, N_, D_, D2_, 0, D_, 0);
  norm_kernel<<<N_, 256, 0, stream>>>(zbuf, out);
}